// Round 9
// baseline (236.443 us; speedup 1.0000x reference)
//
#include <hip/hip_runtime.h>
#include <math.h>

typedef __bf16 bf16_t;
typedef __bf16 bf16x4 __attribute__((ext_vector_type(4)));
typedef __bf16 bf16x8 __attribute__((ext_vector_type(8)));
typedef float floatx4 __attribute__((ext_vector_type(4)));

#define MFMA16(A, B, C) __builtin_amdgcn_mfma_f32_16x16x32_bf16((A), (B), (C), 0, 0, 0)

static constexpr int BB  = 2;
static constexpr int NH  = 12;
static constexpr int HD  = 64;
static constexpr int DIM = 768;    // NH*HD
static constexpr int QS  = 1568;   // 8*14*14
static constexpr int KS  = 1568;
static constexpr int KSP = 1664;   // padded key stride for vT
static constexpr int MROWS = BB * QS;  // 3136
static constexpr int KT  = 32;     // attention K-tile; 49 iters EXACT, no mask
static constexpr int TD  = 80;     // padded concatenated table rows (69 used)
static constexpr int NUNITS = 24 * 25;  // attn work units: (bn, q-tile)

static constexpr float LOG2E = 1.4426950408889634f;
static constexpr float SCALE_L2E = 0.125f * LOG2E;   // 1/sqrt(64) * log2(e)

// async global->LDS, 16B per lane (LDS dest must be wave-uniform base + lane*16)
__device__ __forceinline__ void async16(const void* g, void* l) {
    __builtin_amdgcn_global_load_lds(
        (const __attribute__((address_space(1))) unsigned int*)g,
        (__attribute__((address_space(3))) unsigned int*)l, 16, 0, 0);
}

// ---------------------------------------------------------------------------
// Prep kernel: (a) weights f32->bf16, (b) q/k inputs f32->bf16, (c) key-side
// one-hot extension table koh, (d) concatenated rel-pos table T[80][64] bf16
// with LOG2E folded, (e) vT key-padding zero-fill, (f) zero the attn
// work-stealing counter (re-zeroed every launch for graph replay).
// ---------------------------------------------------------------------------
__global__ __launch_bounds__(256) void cvt_w(
    const float* __restrict__ q, const float* __restrict__ k,
    const float* __restrict__ wq, const float* __restrict__ wk,
    const float* __restrict__ wv, const float* __restrict__ wo,
    const float* __restrict__ rpt, const float* __restrict__ rph,
    const float* __restrict__ rpw,
    bf16_t* __restrict__ Wb, bf16_t* __restrict__ qb, bf16_t* __restrict__ kb,
    bf16_t* __restrict__ koh, bf16_t* __restrict__ Tt, bf16_t* __restrict__ vT,
    int* __restrict__ ctr)
{
    const int NW4 = DIM * DIM / 4;     // 147456 float4 per weight matrix
    const int NX4 = MROWS * DIM / 4;   // 602112 float4 per input
    const int PADC = (KSP - KS) / 8;   // 12 pad chunks per vT row
    int i = blockIdx.x * 256 + threadIdx.x;
    if (i == 0) *ctr = 0;
    if (i < 4 * NW4) {
        const int w = i / NW4;
        const int off = i - w * NW4;
        const float* src = (w == 0) ? wq : (w == 1) ? wk : (w == 2) ? wv : wo;
        floatx4 v = ((const floatx4*)src)[off];
        bf16x4 o;
#pragma unroll
        for (int r = 0; r < 4; ++r) o[r] = (bf16_t)v[r];
        ((bf16x4*)(Wb + (size_t)w * DIM * DIM))[off] = o;
        return;
    }
    i -= 4 * NW4;
    if (i < 2 * NX4) {
        const float* src = (i < NX4) ? q : k;
        bf16_t* dst = (i < NX4) ? qb : kb;
        const int off = (i < NX4) ? i : i - NX4;
        floatx4 v = ((const floatx4*)src)[off];
        bf16x4 o;
#pragma unroll
        for (int r = 0; r < 4; ++r) o[r] = (bf16_t)v[r];
        ((bf16x4*)dst)[off] = o;
        return;
    }
    i -= 2 * NX4;
    if (i < KS) {
        const int key = i;
        const int tk = key / 196;
        const int rem = key - tk * 196;
        const int hk = rem / 14;
        const int wk_ = rem - hk * 14;
#pragma unroll
        for (int c8 = 0; c8 < 8; ++c8) {
            bf16x8 v;
#pragma unroll
            for (int j = 0; j < 8; ++j) {
                const int e = c8 * 8 + j;
                const float f = (e == tk || e == 8 + hk || e == 22 + wk_) ? 1.f : 0.f;
                v[j] = (bf16_t)f;
            }
            *(bf16x8*)(koh + (size_t)key * 64 + c8 * 8) = v;
        }
        return;
    }
    i -= KS;
    if (i < TD * 8) {
        const int d = i >> 3;
        const int c8 = (i & 7) * 8;
        bf16x8 v;
#pragma unroll
        for (int j = 0; j < 8; ++j) {
            const int c = c8 + j;
            float f = 0.f;
            if (d < 15)      f = LOG2E * rpt[(size_t)d * 64 + c];
            else if (d < 42) f = LOG2E * rph[(size_t)(d - 15) * 64 + c];
            else if (d < 69) f = LOG2E * rpw[(size_t)(d - 42) * 64 + c];
            v[j] = (bf16_t)f;
        }
        *(bf16x8*)(Tt + (size_t)d * 64 + c8) = v;
        return;
    }
    i -= TD * 8;
    if (i < BB * NH * HD * PADC) {
        const int row = i / PADC;
        const int ch  = i - row * PADC;
        bf16x8 z;
#pragma unroll
        for (int r = 0; r < 8; ++r) z[r] = (bf16_t)0.f;
        *(bf16x8*)(vT + (size_t)row * KSP + KS + ch * 8) = z;
    }
}

// ---------------------------------------------------------------------------
// Fused Q/K/V projection GEMM (unchanged, round-4 proven): Y = X @ W^T + b.
// Tile 128x64, BK=64, dbuf async16 staging, XOR chunk swizzle.
// K output pre-scaled by SCALE_L2E.
// ---------------------------------------------------------------------------
__global__ __launch_bounds__(256) void gemm_qkv(
    const bf16_t* __restrict__ qb, const bf16_t* __restrict__ kb,
    const bf16_t* __restrict__ Wb,
    const float* __restrict__ bq, const float* __restrict__ bk,
    const float* __restrict__ bv,
    bf16_t* __restrict__ qhP, bf16_t* __restrict__ khP, bf16_t* __restrict__ vT)
{
    __shared__ __align__(16) bf16_t Asa[128 * 64];  // 16 KB each
    __shared__ __align__(16) bf16_t Asb[128 * 64];
    __shared__ __align__(16) bf16_t Bsa[64 * 64];   // 8 KB each
    __shared__ __align__(16) bf16_t Bsb[64 * 64];

    const int tid   = threadIdx.x;
    const int lane  = tid & 63;
    const int wave  = tid >> 6;
    const int row16 = lane & 15;
    const int quad  = lane >> 4;
    const int wm    = wave & 1;
    const int wn    = wave >> 1;
    const int m0 = blockIdx.x * 128;
    const int yb = blockIdx.y;
    const int proj = yb / 12;
    const int n0 = (yb - proj * 12) * 64;

    const bf16_t* X = (proj == 0) ? qb : kb;
    const bf16_t* W = Wb + (size_t)proj * DIM * DIM;
    const float* bias = (proj == 0) ? bq : (proj == 1) ? bk : bv;
    const float osc = (proj == 1) ? SCALE_L2E : 1.0f;

    floatx4 acc[4][2];
#pragma unroll
    for (int mt = 0; mt < 4; ++mt)
#pragma unroll
        for (int nt = 0; nt < 2; ++nt) acc[mt][nt] = (floatx4){0.f, 0.f, 0.f, 0.f};

    auto stage = [&](int k0, bf16_t* An, bf16_t* Bn) {
#pragma unroll
        for (int p = 0; p < 4; ++p) {
            const int s = p * 256 + tid;            // 0..1023: A 128 rows x 8 chunks
            const int row = s >> 3, c = s & 7;
            const int g = c ^ (row & 7);
            const int rowc = min(m0 + row, MROWS - 1);
            async16(X + (size_t)rowc * DIM + k0 + g * 8, An + s * 8);
        }
#pragma unroll
        for (int p = 0; p < 2; ++p) {
            const int s = p * 256 + tid;            // 0..511: B 64 rows x 8 chunks
            const int row = s >> 3, c = s & 7;
            const int g = c ^ (row & 7);
            async16(W + (size_t)(n0 + row) * DIM + k0 + g * 8, Bn + s * 8);
        }
    };

    auto body = [&](int k0, const bf16_t* Ac, const bf16_t* Bc,
                    bf16_t* An, bf16_t* Bn, bool pf) {
        __syncthreads();
        if (pf) stage(k0 + 64, An, Bn);
#pragma unroll
        for (int h = 0; h < 2; ++h) {
            const int pa = (h * 4 + quad) ^ (row16 & 7);
            bf16x8 aF[4], bF[2];
#pragma unroll
            for (int mt = 0; mt < 4; ++mt) {
                const int rowA = wm * 64 + mt * 16 + row16;
                aF[mt] = *(const bf16x8*)&Ac[rowA * 64 + pa * 8];
            }
#pragma unroll
            for (int nt = 0; nt < 2; ++nt) {
                const int rowB = wn * 32 + nt * 16 + row16;
                bF[nt] = *(const bf16x8*)&Bc[rowB * 64 + pa * 8];
            }
#pragma unroll
            for (int mt = 0; mt < 4; ++mt)
#pragma unroll
                for (int nt = 0; nt < 2; ++nt)
                    acc[mt][nt] = MFMA16(aF[mt], bF[nt], acc[mt][nt]);
        }
    };

    stage(0, Asa, Bsa);
    for (int ii = 0; ii < 6; ++ii) {
        const int k0 = ii * 128;
        body(k0,      Asa, Bsa, Asb, Bsb, true);
        body(k0 + 64, Asb, Bsb, Asa, Bsa, k0 + 128 < DIM);
    }

#pragma unroll
    for (int nt = 0; nt < 2; ++nt) {
        const int col = n0 + wn * 32 + nt * 16 + row16;
        const int head = col >> 6, cl = col & 63;
        const float bv_ = bias[col];
#pragma unroll
        for (int mt = 0; mt < 4; ++mt) {
            const int row0 = m0 + wm * 64 + mt * 16 + quad * 4;
            if (row0 < MROWS) {
                const int bb = (row0 >= KS) ? 1 : 0;
                const int key0 = row0 - bb * KS;
                if (proj == 2) {
                    bf16x4 pv;
#pragma unroll
                    for (int r = 0; r < 4; ++r) pv[r] = (bf16_t)(acc[mt][nt][r] + bv_);
                    *(bf16x4*)&vT[((size_t)(bb * NH + head) * 64 + cl) * KSP + key0] = pv;
                } else {
                    bf16_t* dst = (proj == 0) ? qhP : khP;
#pragma unroll
                    for (int r = 0; r < 4; ++r)
                        dst[((size_t)(bb * NH + head) * KS + key0 + r) * 64 + cl] =
                            (bf16_t)((acc[mt][nt][r] + bv_) * osc);
                }
            }
        }
    }
}

// ---------------------------------------------------------------------------
// Q-side extension, MFMA form (unchanged). G[row][d] = qh[row] . T[d], then
// gather Qe[row][e] = G[row][map(e,row)] through LDS.
// ---------------------------------------------------------------------------
__global__ __launch_bounds__(256) void qext(
    const bf16_t* __restrict__ qhP, const bf16_t* __restrict__ Tt,
    bf16_t* __restrict__ Qe)
{
    __shared__ float Gs[64][81];

    const int tid   = threadIdx.x;
    const int lane  = tid & 63;
    const int wave  = tid >> 6;
    const int row16 = lane & 15;
    const int quad  = lane >> 4;
    const int m0 = blockIdx.x * 64;

    const bf16_t* ap = qhP + (size_t)(m0 + wave * 16 + row16) * 64 + quad * 8;
    bf16x8 a0 = *(const bf16x8*)(ap);
    bf16x8 a1 = *(const bf16x8*)(ap + 32);

    floatx4 acc[5];
#pragma unroll
    for (int t = 0; t < 5; ++t) {
        const bf16_t* tp = Tt + (size_t)(t * 16 + row16) * 64 + quad * 8;
        floatx4 s = (floatx4){0.f, 0.f, 0.f, 0.f};
        s = MFMA16(a0, *(const bf16x8*)(tp), s);
        s = MFMA16(a1, *(const bf16x8*)(tp + 32), s);
        acc[t] = s;
    }
#pragma unroll
    for (int t = 0; t < 5; ++t)
#pragma unroll
        for (int r = 0; r < 4; ++r)
            Gs[wave * 16 + quad * 4 + r][t * 16 + row16] = acc[t][r];
    __syncthreads();

#pragma unroll
    for (int ii = 0; ii < 16; ++ii) {
        const int i = ii * 256 + tid;
        const int row = i >> 6, e = i & 63;
        const int grow = m0 + row;
        const int qg = grow % QS;
        const int tq = qg / 196;
        const int rem = qg - tq * 196;
        const int hq = rem / 14;
        const int wq = rem - hq * 14;
        int d;
        if (e < 8)       d = tq - e + 7;
        else if (e < 22) d = 15 + hq - (e - 8) + 13;
        else             d = 42 + wq - (e - 22) + 13;
        const float val = (e < 36) ? Gs[row][d] : 0.f;
        Qe[(size_t)grow * 64 + e] = (bf16_t)val;
    }
}

// ---------------------------------------------------------------------------
// Fused flash attention with MFMA-folded rel-pos bias — champion r4 block
// internals, now WORK-STEALING: grid 512 (2 blocks/CU exactly); each block
// loops over units u = atomicAdd(ctr) of the 600 (bn, q-tile) units.
// Fixes the static 3-vs-2 blocks/CU imbalance (88 CUs carried 1.5x work).
// Units bn-major so temporally-adjacent grabs share K/V (L3-resident; dbuf
// prefetch hides L3 latency). s_setprio(1) wraps the MFMA clusters (T5).
// ---------------------------------------------------------------------------
__global__ __launch_bounds__(256, 2) void attn_fused(
    const bf16_t* __restrict__ qhP, const bf16_t* __restrict__ Qe,
    const bf16_t* __restrict__ khP, const bf16_t* __restrict__ koh,
    const bf16_t* __restrict__ vT, bf16_t* __restrict__ ao,
    int* __restrict__ ctr)
{
    __shared__ __align__(16) bf16_t KsA[32 * 128];  // 8 KB each (K~ tile)
    __shared__ __align__(16) bf16_t KsB[32 * 128];
    __shared__ __align__(16) bf16_t VsA[64 * 32];   // 4 KB each
    __shared__ __align__(16) bf16_t VsB[64 * 32];
    __shared__ __align__(16) bf16_t Pl[4 * 16 * 40];// 5.1 KB: per-wave P
    __shared__ int s_unit;

    const int tid   = threadIdx.x;
    const int lane  = tid & 63;
    const int wave  = tid >> 6;
    const int row16 = lane & 15;
    const int quad  = lane >> 4;
    const int pbase = wave * 16 * 40;
    const int sw3 = row16 & 7;          // K~ read swizzle
    const int sw2 = (row16 >> 1) & 3;   // V read swizzle

    for (;;) {
        if (tid == 0) s_unit = atomicAdd(ctr, 1);
        __syncthreads();   // broadcast unit; prior unit's LDS readers done
        const int u = s_unit;
        if (u >= NUNITS) return;
        const int bn = u / 25;              // bn-major
        const int q0 = (u - bn * 25) * 64;  // 25 tiles of 64 rows
        const int b = bn / NH;
        const int n = bn - b * NH;

        // persistent Q~ fragments: wave's 16 q-rows (clamped), 128 dims
        const int qrow = min(q0 + wave * 16 + row16, QS - 1);
        const bf16_t* qp = qhP + ((size_t)bn * QS + qrow) * 64 + quad * 8;
        const bf16_t* qe = Qe  + ((size_t)bn * QS + qrow) * 64 + quad * 8;
        bf16x8 aQ0 = *(const bf16x8*)(qp);
        bf16x8 aQ1 = *(const bf16x8*)(qp + 32);
        bf16x8 aQ2 = *(const bf16x8*)(qe);
        bf16x8 aQ3 = *(const bf16x8*)(qe + 32);

        floatx4 O[4];
#pragma unroll
        for (int ct = 0; ct < 4; ++ct) O[ct] = (floatx4){0.f, 0.f, 0.f, 0.f};
        float lsum[4] = {0.f, 0.f, 0.f, 0.f};

        const bf16_t* khb = khP + (size_t)bn * KS * 64;
        const bf16_t* vTb = vT + (size_t)bn * 64 * KSP;

        auto stageKV = [&](int k0, bf16_t* Kn, bf16_t* Vn) {
#pragma unroll
            for (int p = 0; p < 2; ++p) {
                const int s = p * 256 + tid;            // 0..511
                const int row = s >> 4, c = s & 15;
                const int l = c ^ (row & 7);            // low-3-bit XOR keeps halves
                const bf16_t* src = (l < 8)
                    ? khb + (size_t)(k0 + row) * 64 + l * 8
                    : koh + (size_t)(k0 + row) * 64 + (l - 8) * 8;
                async16(src, Kn + s * 8);
            }
            {
                const int row = tid >> 2, c = tid & 3;  // 64 rows x 4 chunks
                const int l = c ^ ((row >> 1) & 3);
                async16(vTb + (size_t)row * KSP + k0 + l * 8, Vn + tid * 8);
            }
        };

        auto iter = [&](int ki, const bf16_t* Kc, const bf16_t* Vc,
                        bf16_t* Kn, bf16_t* Vn, bool pf) {
            const int k0 = ki * KT;
            __syncthreads();   // stage(ki) landed (vmcnt drain); prior readers done
            if (pf) stageKV(k0 + KT, Kn, Vn);

            floatx4 S[2];
            __builtin_amdgcn_s_setprio(1);
#pragma unroll
            for (int t = 0; t < 2; ++t) {
                const bf16_t* kp_ = &Kc[(t * 16 + row16) * 128];
                floatx4 s = (floatx4){0.f, 0.f, 0.f, 0.f};
                s = MFMA16(aQ0, *(const bf16x8*)&kp_[((0 + quad) ^ sw3) * 8], s);
                s = MFMA16(aQ1, *(const bf16x8*)&kp_[((4 + quad) ^ sw3) * 8], s);
                s = MFMA16(aQ2, *(const bf16x8*)&kp_[((8 + quad) ^ sw3) * 8], s);
                s = MFMA16(aQ3, *(const bf16x8*)&kp_[((12 + quad) ^ sw3) * 8], s);
                S[t] = s;
            }
            __builtin_amdgcn_s_setprio(0);

#pragma unroll
            for (int t = 0; t < 2; ++t) {
#pragma unroll
                for (int r = 0; r < 4; ++r) {
                    float p = __builtin_amdgcn_exp2f(S[t][r]);
                    lsum[r] += p;
                    Pl[pbase + (quad * 4 + r) * 40 + t * 16 + row16] = (bf16_t)p;
                }
            }

            bf16x8 aP = *(const bf16x8*)&Pl[pbase + row16 * 40 + quad * 8];
            __builtin_amdgcn_s_setprio(1);
#pragma unroll
            for (int ct = 0; ct < 4; ++ct) {
                bf16x8 bV = *(const bf16x8*)&Vc[(ct * 16 + row16) * 32 + (quad ^ sw2) * 8];
                O[ct] = MFMA16(aP, bV, O[ct]);
            }
            __builtin_amdgcn_s_setprio(0);
        };

        stageKV(0, KsA, VsA);
#pragma unroll 1
        for (int kp2 = 0; kp2 < 24; ++kp2) {
            iter(2 * kp2,     KsA, VsA, KsB, VsB, true);
            iter(2 * kp2 + 1, KsB, VsB, KsA, VsA, true);
        }
        iter(48, KsA, VsA, KsB, VsB, false);

        // epilogue: reduce l across the 16-lane key group, normalize, store
        float inv[4];
#pragma unroll
        for (int r = 0; r < 4; ++r) {
            float l = lsum[r];
            l += __shfl_xor(l, 1);
            l += __shfl_xor(l, 2);
            l += __shfl_xor(l, 4);
            l += __shfl_xor(l, 8);
            inv[r] = 1.f / l;
        }
#pragma unroll
        for (int ct = 0; ct < 4; ++ct) {
            const int c = n * HD + ct * 16 + row16;
#pragma unroll
            for (int r = 0; r < 4; ++r) {
                const int qr = q0 + wave * 16 + quad * 4 + r;
                if (qr < QS)
                    ao[(size_t)(b * QS + qr) * DIM + c] = (bf16_t)(O[ct][r] * inv[r]);
            }
        }
    }
}

// ---------------------------------------------------------------------------
// O-projection GEMM — round-4 64x64 version restored (588 blocks = 2.3/CU;
// the 128x64 retile dropped to 300 blocks = 1.17/CU and cost ~3 µs).
// Y(f32) = X(bf16) @ Wo^T + bo.
// ---------------------------------------------------------------------------
__global__ __launch_bounds__(256) void gemm_o(
    const bf16_t* __restrict__ X, const bf16_t* __restrict__ W,
    const float* __restrict__ bias, float* __restrict__ Y)
{
    __shared__ __align__(16) bf16_t Asa[64 * 64];
    __shared__ __align__(16) bf16_t Asb[64 * 64];
    __shared__ __align__(16) bf16_t Bsa[64 * 64];
    __shared__ __align__(16) bf16_t Bsb[64 * 64];

    const int tid   = threadIdx.x;
    const int lane  = tid & 63;
    const int wave  = tid >> 6;
    const int row16 = lane & 15;
    const int quad  = lane >> 4;
    const int m0 = blockIdx.x * 64;
    const int n0 = blockIdx.y * 64;

    floatx4 acc[4];
#pragma unroll
    for (int nt = 0; nt < 4; ++nt) acc[nt] = (floatx4){0.f, 0.f, 0.f, 0.f};

    auto stage = [&](int k0, bf16_t* An, bf16_t* Bn) {
#pragma unroll
        for (int p = 0; p < 2; ++p) {
            const int s = p * 256 + tid;
            const int row = s >> 3, pc = s & 7;
            const int g = pc ^ (row & 7);
            async16(X + (size_t)(m0 + row) * DIM + k0 + g * 8, An + s * 8);
            async16(W + (size_t)(n0 + row) * DIM + k0 + g * 8, Bn + s * 8);
        }
    };

    auto body = [&](int k0, const bf16_t* Ac, const bf16_t* Bc,
                    bf16_t* An, bf16_t* Bn, bool pf) {
        __syncthreads();
        if (pf) stage(k0 + 64, An, Bn);
#pragma unroll
        for (int h = 0; h < 2; ++h) {
            const int lc = h * 4 + quad;
            const int pa = lc ^ (row16 & 7);
            const int rowA = wave * 16 + row16;
            bf16x8 aF = *(const bf16x8*)&Ac[rowA * 64 + pa * 8];
#pragma unroll
            for (int nt = 0; nt < 4; ++nt) {
                bf16x8 bF = *(const bf16x8*)&Bc[(nt * 16 + row16) * 64 + pa * 8];
                acc[nt] = MFMA16(aF, bF, acc[nt]);
            }
        }
    };

    stage(0, Asa, Bsa);
    for (int ii = 0; ii < 6; ++ii) {
        const int k0 = ii * 128;
        body(k0,      Asa, Bsa, Asb, Bsb, true);
        body(k0 + 64, Asb, Bsb, Asa, Bsa, k0 + 128 < DIM);
    }

#pragma unroll
    for (int nt = 0; nt < 4; ++nt) {
        const int col = n0 + nt * 16 + row16;
        const float bv = bias[col];
#pragma unroll
        for (int r = 0; r < 4; ++r) {
            const int row = m0 + wave * 16 + quad * 4 + r;
            Y[(size_t)row * DIM + col] = acc[nt][r] + bv;
        }
    }
}

// ---------------------------------------------------------------------------
extern "C" void kernel_launch(void* const* d_in, const int* in_sizes, int n_in,
                              void* d_out, int out_size, void* d_ws, size_t ws_size,
                              hipStream_t stream) {
    const float* q   = (const float*)d_in[0];
    const float* k   = (const float*)d_in[1];
    const float* Wq  = (const float*)d_in[2];
    const float* bq  = (const float*)d_in[3];
    const float* Wk  = (const float*)d_in[4];
    const float* bk  = (const float*)d_in[5];
    const float* Wv  = (const float*)d_in[6];
    const float* bv  = (const float*)d_in[7];
    const float* Wo  = (const float*)d_in[8];
    const float* bo  = (const float*)d_in[9];
    const float* rpt = (const float*)d_in[10];
    const float* rph = (const float*)d_in[11];
    const float* rpw = (const float*)d_in[12];

    // workspace (~29.3 MB + ctr). Aliases (stream-order lifetimes disjoint):
    //   QeKb: kb (read by gemm_qkv) then Qe (written by qext)
    //   aoQb: qb (read by gemm_qkv) then ao (written by attn)
    bf16_t* qhP  = (bf16_t*)d_ws;
    bf16_t* khP  = qhP  + (size_t)MROWS * DIM;
    bf16_t* vT   = khP  + (size_t)MROWS * DIM;
    bf16_t* QeKb = vT   + (size_t)BB * NH * HD * KSP;
    bf16_t* aoQb = QeKb + (size_t)MROWS * DIM;
    bf16_t* koh  = aoQb + (size_t)MROWS * DIM;
    bf16_t* Tt   = koh  + (size_t)KS * 64;
    bf16_t* Wb   = Tt   + (size_t)TD * 64;        // [Wq|Wk|Wv|Wo]
    int*    ctr  = (int*)(Wb + (size_t)4 * DIM * DIM);

    const int NW4 = DIM * DIM / 4;
    const int NX4 = MROWS * DIM / 4;
    const int PADC = (KSP - KS) / 8;
    const int NCVT = 4 * NW4 + 2 * NX4 + KS + TD * 8 + BB * NH * HD * PADC;
    cvt_w<<<(NCVT + 255) / 256, 256, 0, stream>>>(
        q, k, Wq, Wk, Wv, Wo, rpt, rph, rpw, Wb, aoQb, QeKb, koh, Tt, vT, ctr);

    gemm_qkv<<<dim3(25, 36), 256, 0, stream>>>(
        aoQb, QeKb, Wb, bq, bk, bv, qhP, khP, vT);

    qext<<<(BB * NH * QS) / 64, 256, 0, stream>>>(qhP, Tt, QeKb);

    attn_fused<<<dim3(512), 256, 0, stream>>>(
        qhP, QeKb, khP, koh, vT, aoQb, ctr);

    gemm_o<<<dim3(MROWS / 64, DIM / 64), 256, 0, stream>>>(
        aoQb, Wb + (size_t)3 * DIM * DIM, bo, (float*)d_out);
}

// Round 10
// 205.130 us; speedup vs baseline: 1.1526x; 1.1526x over previous
//
#include <hip/hip_runtime.h>
#include <math.h>

typedef __bf16 bf16_t;
typedef __bf16 bf16x4 __attribute__((ext_vector_type(4)));
typedef __bf16 bf16x8 __attribute__((ext_vector_type(8)));
typedef float floatx4 __attribute__((ext_vector_type(4)));

#define MFMA16(A, B, C) __builtin_amdgcn_mfma_f32_16x16x32_bf16((A), (B), (C), 0, 0, 0)

static constexpr int BB  = 2;
static constexpr int NH  = 12;
static constexpr int HD  = 64;
static constexpr int DIM = 768;    // NH*HD
static constexpr int QS  = 1568;   // 8*14*14
static constexpr int KS  = 1568;
static constexpr int KSP = 1664;   // padded key stride for vT
static constexpr int MROWS = BB * QS;  // 3136
static constexpr int KT  = 32;     // attention K-tile; 49 iters EXACT, no mask
static constexpr int TD  = 80;     // padded concatenated table rows (69 used)

static constexpr float LOG2E = 1.4426950408889634f;
static constexpr float SCALE_L2E = 0.125f * LOG2E;   // 1/sqrt(64) * log2(e)

// async global->LDS, 16B per lane (LDS dest must be wave-uniform base + lane*16)
__device__ __forceinline__ void async16(const void* g, void* l) {
    __builtin_amdgcn_global_load_lds(
        (const __attribute__((address_space(1))) unsigned int*)g,
        (__attribute__((address_space(3))) unsigned int*)l, 16, 0, 0);
}

// ---------------------------------------------------------------------------
// Prep kernel: (a) weights f32->bf16, (b) q/k inputs f32->bf16, (c) key-side
// one-hot extension table koh, (d) concatenated rel-pos table T[80][64] bf16
// with LOG2E folded (rows: 0..14 = rpt, 15..41 = rph, 42..68 = rpw, rest 0).
// ---------------------------------------------------------------------------
__global__ __launch_bounds__(256) void cvt_w(
    const float* __restrict__ q, const float* __restrict__ k,
    const float* __restrict__ wq, const float* __restrict__ wk,
    const float* __restrict__ wv, const float* __restrict__ wo,
    const float* __restrict__ rpt, const float* __restrict__ rph,
    const float* __restrict__ rpw,
    bf16_t* __restrict__ Wb, bf16_t* __restrict__ qb, bf16_t* __restrict__ kb,
    bf16_t* __restrict__ koh, bf16_t* __restrict__ Tt)
{
    const int NW4 = DIM * DIM / 4;     // 147456 float4 per weight matrix
    const int NX4 = MROWS * DIM / 4;   // 602112 float4 per input
    int i = blockIdx.x * 256 + threadIdx.x;
    if (i < 4 * NW4) {
        const int w = i / NW4;
        const int off = i - w * NW4;
        const float* src = (w == 0) ? wq : (w == 1) ? wk : (w == 2) ? wv : wo;
        floatx4 v = ((const floatx4*)src)[off];
        bf16x4 o;
#pragma unroll
        for (int r = 0; r < 4; ++r) o[r] = (bf16_t)v[r];
        ((bf16x4*)(Wb + (size_t)w * DIM * DIM))[off] = o;
        return;
    }
    i -= 4 * NW4;
    if (i < 2 * NX4) {
        const float* src = (i < NX4) ? q : k;
        bf16_t* dst = (i < NX4) ? qb : kb;
        const int off = (i < NX4) ? i : i - NX4;
        floatx4 v = ((const floatx4*)src)[off];
        bf16x4 o;
#pragma unroll
        for (int r = 0; r < 4; ++r) o[r] = (bf16_t)v[r];
        ((bf16x4*)dst)[off] = o;
        return;
    }
    i -= 2 * NX4;
    if (i < KS) {
        const int key = i;
        const int tk = key / 196;
        const int rem = key - tk * 196;
        const int hk = rem / 14;
        const int wk_ = rem - hk * 14;
#pragma unroll
        for (int c8 = 0; c8 < 8; ++c8) {
            bf16x8 v;
#pragma unroll
            for (int j = 0; j < 8; ++j) {
                const int e = c8 * 8 + j;
                const float f = (e == tk || e == 8 + hk || e == 22 + wk_) ? 1.f : 0.f;
                v[j] = (bf16_t)f;
            }
            *(bf16x8*)(koh + (size_t)key * 64 + c8 * 8) = v;
        }
        return;
    }
    i -= KS;
    if (i < TD * 8) {
        const int d = i >> 3;
        const int c8 = (i & 7) * 8;
        bf16x8 v;
#pragma unroll
        for (int j = 0; j < 8; ++j) {
            const int c = c8 + j;
            float f = 0.f;
            if (d < 15)      f = LOG2E * rpt[(size_t)d * 64 + c];
            else if (d < 42) f = LOG2E * rph[(size_t)(d - 15) * 64 + c];
            else if (d < 69) f = LOG2E * rpw[(size_t)(d - 42) * 64 + c];
            v[j] = (bf16_t)f;
        }
        *(bf16x8*)(Tt + (size_t)d * 64 + c8) = v;
    }
}

// ---------------------------------------------------------------------------
// Fused Q/K/V projection GEMM: Y = X @ W^T + b, X bf16 (pre-converted).
// Tile 128x64, BK=64 (12 bodies), dbuf async16 staging, XOR chunk swizzle.
// K output pre-scaled by SCALE_L2E.
// ---------------------------------------------------------------------------
__global__ __launch_bounds__(256) void gemm_qkv(
    const bf16_t* __restrict__ qb, const bf16_t* __restrict__ kb,
    const bf16_t* __restrict__ Wb,
    const float* __restrict__ bq, const float* __restrict__ bk,
    const float* __restrict__ bv,
    bf16_t* __restrict__ qhP, bf16_t* __restrict__ khP, bf16_t* __restrict__ vT)
{
    __shared__ __align__(16) bf16_t Asa[128 * 64];  // 16 KB each
    __shared__ __align__(16) bf16_t Asb[128 * 64];
    __shared__ __align__(16) bf16_t Bsa[64 * 64];   // 8 KB each
    __shared__ __align__(16) bf16_t Bsb[64 * 64];

    const int tid   = threadIdx.x;
    const int lane  = tid & 63;
    const int wave  = tid >> 6;
    const int row16 = lane & 15;
    const int quad  = lane >> 4;
    const int wm    = wave & 1;
    const int wn    = wave >> 1;
    const int m0 = blockIdx.x * 128;
    const int yb = blockIdx.y;
    const int proj = yb / 12;
    const int n0 = (yb - proj * 12) * 64;

    const bf16_t* X = (proj == 0) ? qb : kb;
    const bf16_t* W = Wb + (size_t)proj * DIM * DIM;
    const float* bias = (proj == 0) ? bq : (proj == 1) ? bk : bv;
    const float osc = (proj == 1) ? SCALE_L2E : 1.0f;

    floatx4 acc[4][2];
#pragma unroll
    for (int mt = 0; mt < 4; ++mt)
#pragma unroll
        for (int nt = 0; nt < 2; ++nt) acc[mt][nt] = (floatx4){0.f, 0.f, 0.f, 0.f};

    auto stage = [&](int k0, bf16_t* An, bf16_t* Bn) {
#pragma unroll
        for (int p = 0; p < 4; ++p) {
            const int s = p * 256 + tid;            // 0..1023: A 128 rows x 8 chunks
            const int row = s >> 3, c = s & 7;
            const int g = c ^ (row & 7);
            const int rowc = min(m0 + row, MROWS - 1);
            async16(X + (size_t)rowc * DIM + k0 + g * 8, An + s * 8);
        }
#pragma unroll
        for (int p = 0; p < 2; ++p) {
            const int s = p * 256 + tid;            // 0..511: B 64 rows x 8 chunks
            const int row = s >> 3, c = s & 7;
            const int g = c ^ (row & 7);
            async16(W + (size_t)(n0 + row) * DIM + k0 + g * 8, Bn + s * 8);
        }
    };

    auto body = [&](int k0, const bf16_t* Ac, const bf16_t* Bc,
                    bf16_t* An, bf16_t* Bn, bool pf) {
        __syncthreads();
        if (pf) stage(k0 + 64, An, Bn);
#pragma unroll
        for (int h = 0; h < 2; ++h) {
            const int pa = (h * 4 + quad) ^ (row16 & 7);
            bf16x8 aF[4], bF[2];
#pragma unroll
            for (int mt = 0; mt < 4; ++mt) {
                const int rowA = wm * 64 + mt * 16 + row16;
                aF[mt] = *(const bf16x8*)&Ac[rowA * 64 + pa * 8];
            }
#pragma unroll
            for (int nt = 0; nt < 2; ++nt) {
                const int rowB = wn * 32 + nt * 16 + row16;
                bF[nt] = *(const bf16x8*)&Bc[rowB * 64 + pa * 8];
            }
#pragma unroll
            for (int mt = 0; mt < 4; ++mt)
#pragma unroll
                for (int nt = 0; nt < 2; ++nt)
                    acc[mt][nt] = MFMA16(aF[mt], bF[nt], acc[mt][nt]);
        }
    };

    stage(0, Asa, Bsa);
    for (int ii = 0; ii < 6; ++ii) {
        const int k0 = ii * 128;
        body(k0,      Asa, Bsa, Asb, Bsb, true);
        body(k0 + 64, Asb, Bsb, Asa, Bsa, k0 + 128 < DIM);
    }

#pragma unroll
    for (int nt = 0; nt < 2; ++nt) {
        const int col = n0 + wn * 32 + nt * 16 + row16;
        const int head = col >> 6, cl = col & 63;
        const float bv_ = bias[col];
#pragma unroll
        for (int mt = 0; mt < 4; ++mt) {
            const int row0 = m0 + wm * 64 + mt * 16 + quad * 4;
            if (row0 < MROWS) {
                const int bb = (row0 >= KS) ? 1 : 0;
                const int key0 = row0 - bb * KS;
                if (proj == 2) {
                    bf16x4 pv;
#pragma unroll
                    for (int r = 0; r < 4; ++r) pv[r] = (bf16_t)(acc[mt][nt][r] + bv_);
                    *(bf16x4*)&vT[((size_t)(bb * NH + head) * 64 + cl) * KSP + key0] = pv;
                } else {
                    bf16_t* dst = (proj == 0) ? qhP : khP;
#pragma unroll
                    for (int r = 0; r < 4; ++r)
                        dst[((size_t)(bb * NH + head) * KS + key0 + r) * 64 + cl] =
                            (bf16_t)((acc[mt][nt][r] + bv_) * osc);
                }
            }
        }
    }
}

// ---------------------------------------------------------------------------
// Q-side extension, MFMA form. G[row][d] = qh[row] . T[d]  (T has LOG2E
// folded), then gather Qe[row][e] = G[row][map(e,row)] through LDS.
// Block: 256 thr / 4 waves, 64 rows x 80 d. Grid 37632/64 = 588.
// ---------------------------------------------------------------------------
__global__ __launch_bounds__(256) void qext(
    const bf16_t* __restrict__ qhP, const bf16_t* __restrict__ Tt,
    bf16_t* __restrict__ Qe)
{
    __shared__ float Gs[64][81];   // 20.7 KB, stride 81 breaks bank alignment

    const int tid   = threadIdx.x;
    const int lane  = tid & 63;
    const int wave  = tid >> 6;
    const int row16 = lane & 15;
    const int quad  = lane >> 4;
    const int m0 = blockIdx.x * 64;

    // A frags: wave's 16 q-rows
    const bf16_t* ap = qhP + (size_t)(m0 + wave * 16 + row16) * 64 + quad * 8;
    bf16x8 a0 = *(const bf16x8*)(ap);
    bf16x8 a1 = *(const bf16x8*)(ap + 32);

    floatx4 acc[5];
#pragma unroll
    for (int t = 0; t < 5; ++t) {
        const bf16_t* tp = Tt + (size_t)(t * 16 + row16) * 64 + quad * 8;
        floatx4 s = (floatx4){0.f, 0.f, 0.f, 0.f};
        s = MFMA16(a0, *(const bf16x8*)(tp), s);
        s = MFMA16(a1, *(const bf16x8*)(tp + 32), s);
        acc[t] = s;
    }
#pragma unroll
    for (int t = 0; t < 5; ++t)
#pragma unroll
        for (int r = 0; r < 4; ++r)
            Gs[wave * 16 + quad * 4 + r][t * 16 + row16] = acc[t][r];
    __syncthreads();

#pragma unroll
    for (int ii = 0; ii < 16; ++ii) {
        const int i = ii * 256 + tid;
        const int row = i >> 6, e = i & 63;
        const int grow = m0 + row;
        const int qg = grow % QS;
        const int tq = qg / 196;
        const int rem = qg - tq * 196;
        const int hq = rem / 14;
        const int wq = rem - hq * 14;
        int d;
        if (e < 8)       d = tq - e + 7;
        else if (e < 22) d = 15 + hq - (e - 8) + 13;
        else             d = 42 + wq - (e - 22) + 13;
        const float val = (e < 36) ? Gs[row][d] : 0.f;
        Qe[(size_t)grow * 64 + e] = (bf16_t)val;
    }
}

// ---------------------------------------------------------------------------
// Fused flash attention with MFMA-folded rel-pos bias — the measured champion
// (round 4: 51.0 µs). 256 thr / 4 waves x 16 q-rows, grid 600 XCD-swizzled,
// KT=32 (49 iters exact), 1-barrier dbuf K~+V staged via global_load_lds,
// XOR chunk swizzle (pre-swizzled source, swizzled read).
// Q~ = [qh | Qe] (128), K~ = [SCALE_L2E*kh | onehot] (128):
//   S = Q~ . K~^T IS the exp2 argument — softmax is p = exp2(S), nothing else.
// ---------------------------------------------------------------------------
__global__ __launch_bounds__(256, 2) void attn_fused(
    const bf16_t* __restrict__ qhP, const bf16_t* __restrict__ Qe,
    const bf16_t* __restrict__ khP, const bf16_t* __restrict__ koh,
    const bf16_t* __restrict__ vT, bf16_t* __restrict__ ao)
{
    __shared__ __align__(16) bf16_t KsA[32 * 128];  // 8 KB each (K~ tile)
    __shared__ __align__(16) bf16_t KsB[32 * 128];
    __shared__ __align__(16) bf16_t VsA[64 * 32];   // 4 KB each
    __shared__ __align__(16) bf16_t VsB[64 * 32];
    __shared__ __align__(16) bf16_t Pl[4 * 16 * 40];// 5.1 KB: per-wave P

    const int tid   = threadIdx.x;
    const int lane  = tid & 63;
    const int wave  = tid >> 6;
    const int row16 = lane & 15;
    const int quad  = lane >> 4;

    // XCD swizzle: all 25 q-blocks of one (b,n) share blockIdx%8
    const int L = blockIdx.x;           // 0..599 (= 8 * 3 * 25)
    const int xcd = L & 7;
    const int j = L >> 3;               // 0..74
    const int bn = xcd * 3 + (j % 3);   // 0..23
    const int q0 = (j / 3) * 64;        // 25 tiles of 64 rows (last half-masked)
    const int b = bn / NH;
    const int n = bn - b * NH;

    const int qrow = min(q0 + wave * 16 + row16, QS - 1);
    const bf16_t* qp = qhP + ((size_t)bn * QS + qrow) * 64 + quad * 8;
    const bf16_t* qe = Qe  + ((size_t)bn * QS + qrow) * 64 + quad * 8;
    bf16x8 aQ0 = *(const bf16x8*)(qp);
    bf16x8 aQ1 = *(const bf16x8*)(qp + 32);
    bf16x8 aQ2 = *(const bf16x8*)(qe);
    bf16x8 aQ3 = *(const bf16x8*)(qe + 32);

    floatx4 O[4];
#pragma unroll
    for (int ct = 0; ct < 4; ++ct) O[ct] = (floatx4){0.f, 0.f, 0.f, 0.f};
    float lsum[4] = {0.f, 0.f, 0.f, 0.f};

    const bf16_t* khb = khP + (size_t)bn * KS * 64;
    const bf16_t* vTb = vT + (size_t)bn * 64 * KSP;
    const int pbase = wave * 16 * 40;
    const int sw3 = row16 & 7;          // K~ read swizzle
    const int sw2 = (row16 >> 1) & 3;   // V read swizzle

    // stage K~ (32 keys x 128 dims: cols 0..63 from khP, 64..127 from koh)
    // and V (64 c x 32 keys). LDS linear; source chunk XOR-pre-swizzled.
    auto stageKV = [&](int k0, bf16_t* Kn, bf16_t* Vn) {
#pragma unroll
        for (int p = 0; p < 2; ++p) {
            const int s = p * 256 + tid;            // 0..511
            const int row = s >> 4, c = s & 15;
            const int l = c ^ (row & 7);            // low-3-bit XOR keeps halves
            const bf16_t* src = (l < 8)
                ? khb + (size_t)(k0 + row) * 64 + l * 8
                : koh + (size_t)(k0 + row) * 64 + (l - 8) * 8;
            async16(src, Kn + s * 8);
        }
        {
            const int row = tid >> 2, c = tid & 3;  // 64 rows x 4 chunks
            const int l = c ^ ((row >> 1) & 3);
            async16(vTb + (size_t)row * KSP + k0 + l * 8, Vn + tid * 8);
        }
    };

    auto iter = [&](int ki, const bf16_t* Kc, const bf16_t* Vc,
                    bf16_t* Kn, bf16_t* Vn, bool pf) {
        const int k0 = ki * KT;
        __syncthreads();   // stage(ki) landed (vmcnt drain); prior readers done
        if (pf) stageKV(k0 + KT, Kn, Vn);   // lands during THIS tile's compute

        // ---- S = Q~ K~^T: 2 key-subtiles of 16, 4 dim-chunks of 32
        floatx4 S[2];
#pragma unroll
        for (int t = 0; t < 2; ++t) {
            const bf16_t* kp_ = &Kc[(t * 16 + row16) * 128];
            floatx4 s = (floatx4){0.f, 0.f, 0.f, 0.f};
            s = MFMA16(aQ0, *(const bf16x8*)&kp_[((0 + quad) ^ sw3) * 8], s);
            s = MFMA16(aQ1, *(const bf16x8*)&kp_[((4 + quad) ^ sw3) * 8], s);
            s = MFMA16(aQ2, *(const bf16x8*)&kp_[((8 + quad) ^ sw3) * 8], s);
            s = MFMA16(aQ3, *(const bf16x8*)&kp_[((12 + quad) ^ sw3) * 8], s);
            S[t] = s;
        }

        // ---- softmax: p = exp2(S); no bias, no mask (49x32 = 1568 exact)
#pragma unroll
        for (int t = 0; t < 2; ++t) {
#pragma unroll
            for (int r = 0; r < 4; ++r) {
                float p = __builtin_amdgcn_exp2f(S[t][r]);
                lsum[r] += p;
                Pl[pbase + (quad * 4 + r) * 40 + t * 16 + row16] = (bf16_t)p;
            }
        }

        // ---- O += P V
        bf16x8 aP = *(const bf16x8*)&Pl[pbase + row16 * 40 + quad * 8];
#pragma unroll
        for (int ct = 0; ct < 4; ++ct) {
            bf16x8 bV = *(const bf16x8*)&Vc[(ct * 16 + row16) * 32 + (quad ^ sw2) * 8];
            O[ct] = MFMA16(aP, bV, O[ct]);
        }
    };

    stageKV(0, KsA, VsA);
#pragma unroll 1
    for (int kp2 = 0; kp2 < 24; ++kp2) {
        iter(2 * kp2,     KsA, VsA, KsB, VsB, true);
        iter(2 * kp2 + 1, KsB, VsB, KsA, VsA, true);
    }
    iter(48, KsA, VsA, KsB, VsB, false);

    // ---- epilogue: reduce l across the 16-lane key group, normalize, store
    float inv[4];
#pragma unroll
    for (int r = 0; r < 4; ++r) {
        float l = lsum[r];
        l += __shfl_xor(l, 1);
        l += __shfl_xor(l, 2);
        l += __shfl_xor(l, 4);
        l += __shfl_xor(l, 8);
        inv[r] = 1.f / l;
    }
#pragma unroll
    for (int ct = 0; ct < 4; ++ct) {
        const int c = n * HD + ct * 16 + row16;
#pragma unroll
        for (int r = 0; r < 4; ++r) {
            const int qr = q0 + wave * 16 + quad * 4 + r;
            if (qr < QS)
                ao[(size_t)(b * QS + qr) * DIM + c] = (bf16_t)(O[ct][r] * inv[r]);
        }
    }
}

// ---------------------------------------------------------------------------
// O-projection GEMM (round-4 proven 64x64 tile, 588 blocks = 2.3/CU):
// Y(f32) = X(bf16) @ Wo^T + bo.
// ---------------------------------------------------------------------------
__global__ __launch_bounds__(256) void gemm_o(
    const bf16_t* __restrict__ X, const bf16_t* __restrict__ W,
    const float* __restrict__ bias, float* __restrict__ Y)
{
    __shared__ __align__(16) bf16_t Asa[64 * 64];
    __shared__ __align__(16) bf16_t Asb[64 * 64];
    __shared__ __align__(16) bf16_t Bsa[64 * 64];
    __shared__ __align__(16) bf16_t Bsb[64 * 64];

    const int tid   = threadIdx.x;
    const int lane  = tid & 63;
    const int wave  = tid >> 6;
    const int row16 = lane & 15;
    const int quad  = lane >> 4;
    const int m0 = blockIdx.x * 64;
    const int n0 = blockIdx.y * 64;

    floatx4 acc[4];
#pragma unroll
    for (int nt = 0; nt < 4; ++nt) acc[nt] = (floatx4){0.f, 0.f, 0.f, 0.f};

    auto stage = [&](int k0, bf16_t* An, bf16_t* Bn) {
#pragma unroll
        for (int p = 0; p < 2; ++p) {
            const int s = p * 256 + tid;
            const int row = s >> 3, pc = s & 7;
            const int g = pc ^ (row & 7);
            async16(X + (size_t)(m0 + row) * DIM + k0 + g * 8, An + s * 8);
            async16(W + (size_t)(n0 + row) * DIM + k0 + g * 8, Bn + s * 8);
        }
    };

    auto body = [&](int k0, const bf16_t* Ac, const bf16_t* Bc,
                    bf16_t* An, bf16_t* Bn, bool pf) {
        __syncthreads();
        if (pf) stage(k0 + 64, An, Bn);
#pragma unroll
        for (int h = 0; h < 2; ++h) {
            const int lc = h * 4 + quad;
            const int pa = lc ^ (row16 & 7);
            const int rowA = wave * 16 + row16;
            bf16x8 aF = *(const bf16x8*)&Ac[rowA * 64 + pa * 8];
#pragma unroll
            for (int nt = 0; nt < 4; ++nt) {
                bf16x8 bF = *(const bf16x8*)&Bc[(nt * 16 + row16) * 64 + pa * 8];
                acc[nt] = MFMA16(aF, bF, acc[nt]);
            }
        }
    };

    stage(0, Asa, Bsa);
    for (int ii = 0; ii < 6; ++ii) {
        const int k0 = ii * 128;
        body(k0,      Asa, Bsa, Asb, Bsb, true);
        body(k0 + 64, Asb, Bsb, Asa, Bsa, k0 + 128 < DIM);
    }

#pragma unroll
    for (int nt = 0; nt < 4; ++nt) {
        const int col = n0 + nt * 16 + row16;
        const float bv = bias[col];
#pragma unroll
        for (int r = 0; r < 4; ++r) {
            const int row = m0 + wave * 16 + quad * 4 + r;
            Y[(size_t)row * DIM + col] = acc[nt][r] + bv;
        }
    }
}

// ---------------------------------------------------------------------------
extern "C" void kernel_launch(void* const* d_in, const int* in_sizes, int n_in,
                              void* d_out, int out_size, void* d_ws, size_t ws_size,
                              hipStream_t stream) {
    const float* q   = (const float*)d_in[0];
    const float* k   = (const float*)d_in[1];
    const float* Wq  = (const float*)d_in[2];
    const float* bq  = (const float*)d_in[3];
    const float* Wk  = (const float*)d_in[4];
    const float* bk  = (const float*)d_in[5];
    const float* Wv  = (const float*)d_in[6];
    const float* bv  = (const float*)d_in[7];
    const float* Wo  = (const float*)d_in[8];
    const float* bo  = (const float*)d_in[9];
    const float* rpt = (const float*)d_in[10];
    const float* rph = (const float*)d_in[11];
    const float* rpw = (const float*)d_in[12];

    // workspace (~29.3 MB). Aliases (stream-order lifetimes disjoint):
    //   QeKb: kb (read by gemm_qkv) then Qe (written by qext)
    //   aoQb: qb (read by gemm_qkv) then ao (written by attn)
    bf16_t* qhP  = (bf16_t*)d_ws;
    bf16_t* khP  = qhP  + (size_t)MROWS * DIM;
    bf16_t* vT   = khP  + (size_t)MROWS * DIM;
    bf16_t* QeKb = vT   + (size_t)BB * NH * HD * KSP;
    bf16_t* aoQb = QeKb + (size_t)MROWS * DIM;
    bf16_t* koh  = aoQb + (size_t)MROWS * DIM;
    bf16_t* Tt   = koh  + (size_t)KS * 64;
    bf16_t* Wb   = Tt   + (size_t)TD * 64;        // [Wq|Wk|Wv|Wo]

    const int NW4 = DIM * DIM / 4;
    const int NX4 = MROWS * DIM / 4;
    const int NCVT = 4 * NW4 + 2 * NX4 + KS + TD * 8;
    cvt_w<<<(NCVT + 255) / 256, 256, 0, stream>>>(
        q, k, Wq, Wk, Wv, Wo, rpt, rph, rpw, Wb, aoQb, QeKb, koh, Tt);

    gemm_qkv<<<dim3(25, 36), 256, 0, stream>>>(
        aoQb, QeKb, Wb, bq, bk, bv, qhP, khP, vT);

    qext<<<(BB * NH * QS) / 64, 256, 0, stream>>>(qhP, Tt, QeKb);

    attn_fused<<<dim3(8 * 3 * 25), 256, 0, stream>>>(
        qhP, QeKb, khP, koh, vT, aoQb);

    gemm_o<<<dim3(MROWS / 64, DIM / 64), 256, 0, stream>>>(
        aoQb, Wb + (size_t)3 * DIM * DIM, bo, (float*)d_out);
}

// Round 11
// 198.352 us; speedup vs baseline: 1.1920x; 1.0342x over previous
//
#include <hip/hip_runtime.h>
#include <math.h>

typedef __bf16 bf16_t;
typedef __bf16 bf16x4 __attribute__((ext_vector_type(4)));
typedef __bf16 bf16x8 __attribute__((ext_vector_type(8)));
typedef float floatx4 __attribute__((ext_vector_type(4)));

#define MFMA16(A, B, C) __builtin_amdgcn_mfma_f32_16x16x32_bf16((A), (B), (C), 0, 0, 0)

static constexpr int BB  = 2;
static constexpr int NH  = 12;
static constexpr int HD  = 64;
static constexpr int DIM = 768;    // NH*HD
static constexpr int QS  = 1568;   // 8*14*14
static constexpr int KS  = 1568;
static constexpr int KSP = 1664;   // padded key stride for vT
static constexpr int MROWS = BB * QS;  // 3136
static constexpr int KT  = 32;     // attention K-tile; 49 iters EXACT, no mask
static constexpr int TD  = 80;     // padded concatenated table rows (69 used)

static constexpr float LOG2E = 1.4426950408889634f;
static constexpr float SCALE_L2E = 0.125f * LOG2E;   // 1/sqrt(64) * log2(e)

// async global->LDS, 16B per lane (LDS dest must be wave-uniform base + lane*16)
__device__ __forceinline__ void async16(const void* g, void* l) {
    __builtin_amdgcn_global_load_lds(
        (const __attribute__((address_space(1))) unsigned int*)g,
        (__attribute__((address_space(3))) unsigned int*)l, 16, 0, 0);
}

// ---------------------------------------------------------------------------
// Prep kernel (unchanged, round-10): (a) weights f32->bf16, (b) q/k inputs
// f32->bf16, (c) key-side one-hot table koh, (d) concatenated rel-pos table
// T[80][64] bf16 with LOG2E folded (0..14 rpt, 15..41 rph, 42..68 rpw).
// ---------------------------------------------------------------------------
__global__ __launch_bounds__(256) void cvt_w(
    const float* __restrict__ q, const float* __restrict__ k,
    const float* __restrict__ wq, const float* __restrict__ wk,
    const float* __restrict__ wv, const float* __restrict__ wo,
    const float* __restrict__ rpt, const float* __restrict__ rph,
    const float* __restrict__ rpw,
    bf16_t* __restrict__ Wb, bf16_t* __restrict__ qb, bf16_t* __restrict__ kb,
    bf16_t* __restrict__ koh, bf16_t* __restrict__ Tt)
{
    const int NW4 = DIM * DIM / 4;     // 147456 float4 per weight matrix
    const int NX4 = MROWS * DIM / 4;   // 602112 float4 per input
    int i = blockIdx.x * 256 + threadIdx.x;
    if (i < 4 * NW4) {
        const int w = i / NW4;
        const int off = i - w * NW4;
        const float* src = (w == 0) ? wq : (w == 1) ? wk : (w == 2) ? wv : wo;
        floatx4 v = ((const floatx4*)src)[off];
        bf16x4 o;
#pragma unroll
        for (int r = 0; r < 4; ++r) o[r] = (bf16_t)v[r];
        ((bf16x4*)(Wb + (size_t)w * DIM * DIM))[off] = o;
        return;
    }
    i -= 4 * NW4;
    if (i < 2 * NX4) {
        const float* src = (i < NX4) ? q : k;
        bf16_t* dst = (i < NX4) ? qb : kb;
        const int off = (i < NX4) ? i : i - NX4;
        floatx4 v = ((const floatx4*)src)[off];
        bf16x4 o;
#pragma unroll
        for (int r = 0; r < 4; ++r) o[r] = (bf16_t)v[r];
        ((bf16x4*)dst)[off] = o;
        return;
    }
    i -= 2 * NX4;
    if (i < KS) {
        const int key = i;
        const int tk = key / 196;
        const int rem = key - tk * 196;
        const int hk = rem / 14;
        const int wk_ = rem - hk * 14;
#pragma unroll
        for (int c8 = 0; c8 < 8; ++c8) {
            bf16x8 v;
#pragma unroll
            for (int j = 0; j < 8; ++j) {
                const int e = c8 * 8 + j;
                const float f = (e == tk || e == 8 + hk || e == 22 + wk_) ? 1.f : 0.f;
                v[j] = (bf16_t)f;
            }
            *(bf16x8*)(koh + (size_t)key * 64 + c8 * 8) = v;
        }
        return;
    }
    i -= KS;
    if (i < TD * 8) {
        const int d = i >> 3;
        const int c8 = (i & 7) * 8;
        bf16x8 v;
#pragma unroll
        for (int j = 0; j < 8; ++j) {
            const int c = c8 + j;
            float f = 0.f;
            if (d < 15)      f = LOG2E * rpt[(size_t)d * 64 + c];
            else if (d < 42) f = LOG2E * rph[(size_t)(d - 15) * 64 + c];
            else if (d < 69) f = LOG2E * rpw[(size_t)(d - 42) * 64 + c];
            v[j] = (bf16_t)f;
        }
        *(bf16x8*)(Tt + (size_t)d * 64 + c8) = v;
    }
}

// ---------------------------------------------------------------------------
// Fused Q/K/V projection GEMM (unchanged, round-10): Y = X @ W^T + b, X bf16.
// Tile 128x64, BK=64 (12 bodies), dbuf async16 staging, XOR chunk swizzle.
// K output pre-scaled by SCALE_L2E.
// ---------------------------------------------------------------------------
__global__ __launch_bounds__(256) void gemm_qkv(
    const bf16_t* __restrict__ qb, const bf16_t* __restrict__ kb,
    const bf16_t* __restrict__ Wb,
    const float* __restrict__ bq, const float* __restrict__ bk,
    const float* __restrict__ bv,
    bf16_t* __restrict__ qhP, bf16_t* __restrict__ khP, bf16_t* __restrict__ vT)
{
    __shared__ __align__(16) bf16_t Asa[128 * 64];  // 16 KB each
    __shared__ __align__(16) bf16_t Asb[128 * 64];
    __shared__ __align__(16) bf16_t Bsa[64 * 64];   // 8 KB each
    __shared__ __align__(16) bf16_t Bsb[64 * 64];

    const int tid   = threadIdx.x;
    const int lane  = tid & 63;
    const int wave  = tid >> 6;
    const int row16 = lane & 15;
    const int quad  = lane >> 4;
    const int wm    = wave & 1;
    const int wn    = wave >> 1;
    const int m0 = blockIdx.x * 128;
    const int yb = blockIdx.y;
    const int proj = yb / 12;
    const int n0 = (yb - proj * 12) * 64;

    const bf16_t* X = (proj == 0) ? qb : kb;
    const bf16_t* W = Wb + (size_t)proj * DIM * DIM;
    const float* bias = (proj == 0) ? bq : (proj == 1) ? bk : bv;
    const float osc = (proj == 1) ? SCALE_L2E : 1.0f;

    floatx4 acc[4][2];
#pragma unroll
    for (int mt = 0; mt < 4; ++mt)
#pragma unroll
        for (int nt = 0; nt < 2; ++nt) acc[mt][nt] = (floatx4){0.f, 0.f, 0.f, 0.f};

    auto stage = [&](int k0, bf16_t* An, bf16_t* Bn) {
#pragma unroll
        for (int p = 0; p < 4; ++p) {
            const int s = p * 256 + tid;            // 0..1023: A 128 rows x 8 chunks
            const int row = s >> 3, c = s & 7;
            const int g = c ^ (row & 7);
            const int rowc = min(m0 + row, MROWS - 1);
            async16(X + (size_t)rowc * DIM + k0 + g * 8, An + s * 8);
        }
#pragma unroll
        for (int p = 0; p < 2; ++p) {
            const int s = p * 256 + tid;            // 0..511: B 64 rows x 8 chunks
            const int row = s >> 3, c = s & 7;
            const int g = c ^ (row & 7);
            async16(W + (size_t)(n0 + row) * DIM + k0 + g * 8, Bn + s * 8);
        }
    };

    auto body = [&](int k0, const bf16_t* Ac, const bf16_t* Bc,
                    bf16_t* An, bf16_t* Bn, bool pf) {
        __syncthreads();
        if (pf) stage(k0 + 64, An, Bn);
#pragma unroll
        for (int h = 0; h < 2; ++h) {
            const int pa = (h * 4 + quad) ^ (row16 & 7);
            bf16x8 aF[4], bF[2];
#pragma unroll
            for (int mt = 0; mt < 4; ++mt) {
                const int rowA = wm * 64 + mt * 16 + row16;
                aF[mt] = *(const bf16x8*)&Ac[rowA * 64 + pa * 8];
            }
#pragma unroll
            for (int nt = 0; nt < 2; ++nt) {
                const int rowB = wn * 32 + nt * 16 + row16;
                bF[nt] = *(const bf16x8*)&Bc[rowB * 64 + pa * 8];
            }
#pragma unroll
            for (int mt = 0; mt < 4; ++mt)
#pragma unroll
                for (int nt = 0; nt < 2; ++nt)
                    acc[mt][nt] = MFMA16(aF[mt], bF[nt], acc[mt][nt]);
        }
    };

    stage(0, Asa, Bsa);
    for (int ii = 0; ii < 6; ++ii) {
        const int k0 = ii * 128;
        body(k0,      Asa, Bsa, Asb, Bsb, true);
        body(k0 + 64, Asb, Bsb, Asa, Bsa, k0 + 128 < DIM);
    }

#pragma unroll
    for (int nt = 0; nt < 2; ++nt) {
        const int col = n0 + wn * 32 + nt * 16 + row16;
        const int head = col >> 6, cl = col & 63;
        const float bv_ = bias[col];
#pragma unroll
        for (int mt = 0; mt < 4; ++mt) {
            const int row0 = m0 + wm * 64 + mt * 16 + quad * 4;
            if (row0 < MROWS) {
                const int bb = (row0 >= KS) ? 1 : 0;
                const int key0 = row0 - bb * KS;
                if (proj == 2) {
                    bf16x4 pv;
#pragma unroll
                    for (int r = 0; r < 4; ++r) pv[r] = (bf16_t)(acc[mt][nt][r] + bv_);
                    *(bf16x4*)&vT[((size_t)(bb * NH + head) * 64 + cl) * KSP + key0] = pv;
                } else {
                    bf16_t* dst = (proj == 0) ? qhP : khP;
#pragma unroll
                    for (int r = 0; r < 4; ++r)
                        dst[((size_t)(bb * NH + head) * KS + key0 + r) * 64 + cl] =
                            (bf16_t)((acc[mt][nt][r] + bv_) * osc);
                }
            }
        }
    }
}

// ---------------------------------------------------------------------------
// Fused flash attention with MFMA-folded rel-pos bias — champion r4/r10 body,
// with the qext KERNEL folded into the block prologue: each block computes
// its own Qe for its 64 q-rows via the verbatim qext MFMA (G = Q . T^T, C
// layout col=d row=qrow) into a Gs[64][81] f32 overlay on the not-yet-used
// Ks/Vs LDS (20.7 KB <= 24 KB), then gathers aQ2/aQ3 straight into
// registers. Deletes one dispatch + the Qe global write/read round-trip.
// Main loop byte-identical to round 10.
// ---------------------------------------------------------------------------
__global__ __launch_bounds__(256, 2) void attn_fused(
    const bf16_t* __restrict__ qhP, const bf16_t* __restrict__ khP,
    const bf16_t* __restrict__ koh, const bf16_t* __restrict__ vT,
    const bf16_t* __restrict__ Tt, bf16_t* __restrict__ ao)
{
    __shared__ __align__(16) unsigned char smem[29696];
    bf16_t* const KsA = (bf16_t*)(smem);            // 8 KB  K~ tile A
    bf16_t* const KsB = (bf16_t*)(smem + 8192);     // 8 KB  K~ tile B
    bf16_t* const VsA = (bf16_t*)(smem + 16384);    // 4 KB  V tile A
    bf16_t* const VsB = (bf16_t*)(smem + 20480);    // 4 KB  V tile B
    bf16_t* const Pl  = (bf16_t*)(smem + 24576);    // 5 KB  per-wave P
    float (*const Gs)[81] = (float(*)[81])smem;     // prologue overlay 20.7 KB

    const int tid   = threadIdx.x;
    const int lane  = tid & 63;
    const int wave  = tid >> 6;
    const int row16 = lane & 15;
    const int quad  = lane >> 4;

    // XCD swizzle: all 25 q-blocks of one (b,n) share blockIdx%8
    const int L = blockIdx.x;           // 0..599 (= 8 * 3 * 25)
    const int xcd = L & 7;
    const int j = L >> 3;               // 0..74
    const int bn = xcd * 3 + (j % 3);   // 0..23
    const int q0 = (j / 3) * 64;        // 25 tiles of 64 rows (last half-masked)
    const int b = bn / NH;
    const int n = bn - b * NH;

    const int qrow = min(q0 + wave * 16 + row16, QS - 1);
    const bf16_t* qp = qhP + ((size_t)bn * QS + qrow) * 64 + quad * 8;
    bf16x8 aQ0 = *(const bf16x8*)(qp);
    bf16x8 aQ1 = *(const bf16x8*)(qp + 32);

    // ---- prologue: in-block Qe (was the qext kernel) -----------------------
    {
        floatx4 g[5];
#pragma unroll
        for (int t = 0; t < 5; ++t) {
            const bf16_t* tp = Tt + (size_t)(t * 16 + row16) * 64 + quad * 8;
            floatx4 s = (floatx4){0.f, 0.f, 0.f, 0.f};
            s = MFMA16(aQ0, *(const bf16x8*)(tp), s);
            s = MFMA16(aQ1, *(const bf16x8*)(tp + 32), s);
            g[t] = s;
        }
#pragma unroll
        for (int t = 0; t < 5; ++t)
#pragma unroll
            for (int r = 0; r < 4; ++r)
                Gs[wave * 16 + quad * 4 + r][t * 16 + row16] = g[t][r];
    }
    __syncthreads();
    bf16x8 aQ2, aQ3;
    {
        const int lrow = wave * 16 + row16;      // Gs row for this lane's qrow
        const int tq = qrow / 196;
        const int rem = qrow - tq * 196;
        const int hq = rem / 14;
        const int wq = rem - hq * 14;
#pragma unroll
        for (int jj = 0; jj < 8; ++jj) {
            const int e = quad * 8 + jj;         // 0..31, all < 36
            const int d = (e < 8)  ? (tq + 7 - e)
                        : (e < 22) ? (hq + 36 - e)
                                   : (wq + 77 - e);
            aQ2[jj] = (bf16_t)Gs[lrow][d];
        }
#pragma unroll
        for (int jj = 0; jj < 8; ++jj) {
            float v = 0.f;
            if (quad == 0 && jj < 4)             // e = 32..35 (w-branch); else 0
                v = Gs[lrow][wq + 77 - (32 + jj)];
            aQ3[jj] = (bf16_t)v;
        }
    }
    __syncthreads();   // all Gs reads done before stageKV(0) overwrites smem

    // ---- main loop (byte-identical to round 10) ----------------------------
    floatx4 O[4];
#pragma unroll
    for (int ct = 0; ct < 4; ++ct) O[ct] = (floatx4){0.f, 0.f, 0.f, 0.f};
    float lsum[4] = {0.f, 0.f, 0.f, 0.f};

    const bf16_t* khb = khP + (size_t)bn * KS * 64;
    const bf16_t* vTb = vT + (size_t)bn * 64 * KSP;
    const int pbase = wave * 16 * 40;
    const int sw3 = row16 & 7;          // K~ read swizzle
    const int sw2 = (row16 >> 1) & 3;   // V read swizzle

    auto stageKV = [&](int k0, bf16_t* Kn, bf16_t* Vn) {
#pragma unroll
        for (int p = 0; p < 2; ++p) {
            const int s = p * 256 + tid;            // 0..511
            const int row = s >> 4, c = s & 15;
            const int l = c ^ (row & 7);            // low-3-bit XOR keeps halves
            const bf16_t* src = (l < 8)
                ? khb + (size_t)(k0 + row) * 64 + l * 8
                : koh + (size_t)(k0 + row) * 64 + (l - 8) * 8;
            async16(src, Kn + s * 8);
        }
        {
            const int row = tid >> 2, c = tid & 3;  // 64 rows x 4 chunks
            const int l = c ^ ((row >> 1) & 3);
            async16(vTb + (size_t)row * KSP + k0 + l * 8, Vn + tid * 8);
        }
    };

    auto iter = [&](int ki, const bf16_t* Kc, const bf16_t* Vc,
                    bf16_t* Kn, bf16_t* Vn, bool pf) {
        const int k0 = ki * KT;
        __syncthreads();   // stage(ki) landed (vmcnt drain); prior readers done
        if (pf) stageKV(k0 + KT, Kn, Vn);   // lands during THIS tile's compute

        floatx4 S[2];
#pragma unroll
        for (int t = 0; t < 2; ++t) {
            const bf16_t* kp_ = &Kc[(t * 16 + row16) * 128];
            floatx4 s = (floatx4){0.f, 0.f, 0.f, 0.f};
            s = MFMA16(aQ0, *(const bf16x8*)&kp_[((0 + quad) ^ sw3) * 8], s);
            s = MFMA16(aQ1, *(const bf16x8*)&kp_[((4 + quad) ^ sw3) * 8], s);
            s = MFMA16(aQ2, *(const bf16x8*)&kp_[((8 + quad) ^ sw3) * 8], s);
            s = MFMA16(aQ3, *(const bf16x8*)&kp_[((12 + quad) ^ sw3) * 8], s);
            S[t] = s;
        }

#pragma unroll
        for (int t = 0; t < 2; ++t) {
#pragma unroll
            for (int r = 0; r < 4; ++r) {
                float p = __builtin_amdgcn_exp2f(S[t][r]);
                lsum[r] += p;
                Pl[pbase + (quad * 4 + r) * 40 + t * 16 + row16] = (bf16_t)p;
            }
        }

        bf16x8 aP = *(const bf16x8*)&Pl[pbase + row16 * 40 + quad * 8];
#pragma unroll
        for (int ct = 0; ct < 4; ++ct) {
            bf16x8 bV = *(const bf16x8*)&Vc[(ct * 16 + row16) * 32 + (quad ^ sw2) * 8];
            O[ct] = MFMA16(aP, bV, O[ct]);
        }
    };

    stageKV(0, KsA, VsA);
#pragma unroll 1
    for (int kp2 = 0; kp2 < 24; ++kp2) {
        iter(2 * kp2,     KsA, VsA, KsB, VsB, true);
        iter(2 * kp2 + 1, KsB, VsB, KsA, VsA, true);
    }
    iter(48, KsA, VsA, KsB, VsB, false);

    // ---- epilogue: reduce l across the 16-lane key group, normalize, store
    float inv[4];
#pragma unroll
    for (int r = 0; r < 4; ++r) {
        float l = lsum[r];
        l += __shfl_xor(l, 1);
        l += __shfl_xor(l, 2);
        l += __shfl_xor(l, 4);
        l += __shfl_xor(l, 8);
        inv[r] = 1.f / l;
    }
#pragma unroll
    for (int ct = 0; ct < 4; ++ct) {
        const int c = n * HD + ct * 16 + row16;
#pragma unroll
        for (int r = 0; r < 4; ++r) {
            const int qr = q0 + wave * 16 + quad * 4 + r;
            if (qr < QS)
                ao[(size_t)(b * QS + qr) * DIM + c] = (bf16_t)(O[ct][r] * inv[r]);
        }
    }
}

// ---------------------------------------------------------------------------
// O-projection GEMM (unchanged, round-10 64x64 tile, 588 blocks = 2.3/CU):
// Y(f32) = X(bf16) @ Wo^T + bo.
// ---------------------------------------------------------------------------
__global__ __launch_bounds__(256) void gemm_o(
    const bf16_t* __restrict__ X, const bf16_t* __restrict__ W,
    const float* __restrict__ bias, float* __restrict__ Y)
{
    __shared__ __align__(16) bf16_t Asa[64 * 64];
    __shared__ __align__(16) bf16_t Asb[64 * 64];
    __shared__ __align__(16) bf16_t Bsa[64 * 64];
    __shared__ __align__(16) bf16_t Bsb[64 * 64];

    const int tid   = threadIdx.x;
    const int lane  = tid & 63;
    const int wave  = tid >> 6;
    const int row16 = lane & 15;
    const int quad  = lane >> 4;
    const int m0 = blockIdx.x * 64;
    const int n0 = blockIdx.y * 64;

    floatx4 acc[4];
#pragma unroll
    for (int nt = 0; nt < 4; ++nt) acc[nt] = (floatx4){0.f, 0.f, 0.f, 0.f};

    auto stage = [&](int k0, bf16_t* An, bf16_t* Bn) {
#pragma unroll
        for (int p = 0; p < 2; ++p) {
            const int s = p * 256 + tid;
            const int row = s >> 3, pc = s & 7;
            const int g = pc ^ (row & 7);
            async16(X + (size_t)(m0 + row) * DIM + k0 + g * 8, An + s * 8);
            async16(W + (size_t)(n0 + row) * DIM + k0 + g * 8, Bn + s * 8);
        }
    };

    auto body = [&](int k0, const bf16_t* Ac, const bf16_t* Bc,
                    bf16_t* An, bf16_t* Bn, bool pf) {
        __syncthreads();
        if (pf) stage(k0 + 64, An, Bn);
#pragma unroll
        for (int h = 0; h < 2; ++h) {
            const int lc = h * 4 + quad;
            const int pa = lc ^ (row16 & 7);
            const int rowA = wave * 16 + row16;
            bf16x8 aF = *(const bf16x8*)&Ac[rowA * 64 + pa * 8];
#pragma unroll
            for (int nt = 0; nt < 4; ++nt) {
                bf16x8 bF = *(const bf16x8*)&Bc[(nt * 16 + row16) * 64 + pa * 8];
                acc[nt] = MFMA16(aF, bF, acc[nt]);
            }
        }
    };

    stage(0, Asa, Bsa);
    for (int ii = 0; ii < 6; ++ii) {
        const int k0 = ii * 128;
        body(k0,      Asa, Bsa, Asb, Bsb, true);
        body(k0 + 64, Asb, Bsb, Asa, Bsa, k0 + 128 < DIM);
    }

#pragma unroll
    for (int nt = 0; nt < 4; ++nt) {
        const int col = n0 + nt * 16 + row16;
        const float bv = bias[col];
#pragma unroll
        for (int r = 0; r < 4; ++r) {
            const int row = m0 + wave * 16 + quad * 4 + r;
            Y[(size_t)row * DIM + col] = acc[nt][r] + bv;
        }
    }
}

// ---------------------------------------------------------------------------
extern "C" void kernel_launch(void* const* d_in, const int* in_sizes, int n_in,
                              void* d_out, int out_size, void* d_ws, size_t ws_size,
                              hipStream_t stream) {
    const float* q   = (const float*)d_in[0];
    const float* k   = (const float*)d_in[1];
    const float* Wq  = (const float*)d_in[2];
    const float* bq  = (const float*)d_in[3];
    const float* Wk  = (const float*)d_in[4];
    const float* bk  = (const float*)d_in[5];
    const float* Wv  = (const float*)d_in[6];
    const float* bv  = (const float*)d_in[7];
    const float* Wo  = (const float*)d_in[8];
    const float* bo  = (const float*)d_in[9];
    const float* rpt = (const float*)d_in[10];
    const float* rph = (const float*)d_in[11];
    const float* rpw = (const float*)d_in[12];

    // workspace (~29.3 MB). Aliases (stream-order lifetimes disjoint):
    //   kbuf: kb (read by gemm_qkv; region formerly also held Qe — now unused after)
    //   aoQb: qb (read by gemm_qkv) then ao (written by attn)
    bf16_t* qhP  = (bf16_t*)d_ws;
    bf16_t* khP  = qhP  + (size_t)MROWS * DIM;
    bf16_t* vT   = khP  + (size_t)MROWS * DIM;
    bf16_t* kbuf = vT   + (size_t)BB * NH * HD * KSP;
    bf16_t* aoQb = kbuf + (size_t)MROWS * DIM;
    bf16_t* koh  = aoQb + (size_t)MROWS * DIM;
    bf16_t* Tt   = koh  + (size_t)KS * 64;
    bf16_t* Wb   = Tt   + (size_t)TD * 64;        // [Wq|Wk|Wv|Wo]

    const int NW4 = DIM * DIM / 4;
    const int NX4 = MROWS * DIM / 4;
    const int NCVT = 4 * NW4 + 2 * NX4 + KS + TD * 8;
    cvt_w<<<(NCVT + 255) / 256, 256, 0, stream>>>(
        q, k, Wq, Wk, Wv, Wo, rpt, rph, rpw, Wb, aoQb, kbuf, koh, Tt);

    gemm_qkv<<<dim3(25, 36), 256, 0, stream>>>(
        aoQb, kbuf, Wb, bq, bk, bv, qhP, khP, vT);

    attn_fused<<<dim3(8 * 3 * 25), 256, 0, stream>>>(
        qhP, khP, koh, vT, Tt, aoQb);

    gemm_o<<<dim3(MROWS / 64, DIM / 64), 256, 0, stream>>>(
        aoQb, Wb + (size_t)3 * DIM * DIM, bo, (float*)d_out);
}

// Round 13
// 197.818 us; speedup vs baseline: 1.1953x; 1.0027x over previous
//
#include <hip/hip_runtime.h>
#include <math.h>

typedef __bf16 bf16_t;
typedef __bf16 bf16x4 __attribute__((ext_vector_type(4)));
typedef __bf16 bf16x8 __attribute__((ext_vector_type(8)));
typedef float floatx4 __attribute__((ext_vector_type(4)));

#define MFMA16(A, B, C) __builtin_amdgcn_mfma_f32_16x16x32_bf16((A), (B), (C), 0, 0, 0)

static constexpr int BB  = 2;
static constexpr int NH  = 12;
static constexpr int HD  = 64;
static constexpr int DIM = 768;    // NH*HD
static constexpr int QS  = 1568;   // 8*14*14
static constexpr int KS  = 1568;
static constexpr int KSP = 1664;   // padded key stride for vT
static constexpr int MROWS = BB * QS;  // 3136
static constexpr int KT  = 32;     // attention K-tile; 49 iters EXACT, no mask
static constexpr int TD  = 80;     // padded concatenated table rows (69 used)

static constexpr float LOG2E = 1.4426950408889634f;
static constexpr float SCALE_L2E = 0.125f * LOG2E;   // 1/sqrt(64) * log2(e)

// async global->LDS, 16B per lane (LDS dest must be wave-uniform base + lane*16)
__device__ __forceinline__ void async16(const void* g, void* l) {
    __builtin_amdgcn_global_load_lds(
        (const __attribute__((address_space(1))) unsigned int*)g,
        (__attribute__((address_space(3))) unsigned int*)l, 16, 0, 0);
}

// ---------------------------------------------------------------------------
// Prep kernel: (a) weights f32->bf16, (b) q/k inputs f32->bf16, (c) key-side
// one-hot table koh, (d) concatenated rel-pos table T[80][64] bf16 with
// LOG2E folded (0..14 rpt, 15..41 rph, 42..68 rpw).
// ---------------------------------------------------------------------------
__global__ __launch_bounds__(256) void cvt_w(
    const float* __restrict__ q, const float* __restrict__ k,
    const float* __restrict__ wq, const float* __restrict__ wk,
    const float* __restrict__ wv, const float* __restrict__ wo,
    const float* __restrict__ rpt, const float* __restrict__ rph,
    const float* __restrict__ rpw,
    bf16_t* __restrict__ Wb, bf16_t* __restrict__ qb, bf16_t* __restrict__ kb,
    bf16_t* __restrict__ koh, bf16_t* __restrict__ Tt)
{
    const int NW4 = DIM * DIM / 4;     // 147456 float4 per weight matrix
    const int NX4 = MROWS * DIM / 4;   // 602112 float4 per input
    int i = blockIdx.x * 256 + threadIdx.x;
    if (i < 4 * NW4) {
        const int w = i / NW4;
        const int off = i - w * NW4;
        const float* src = (w == 0) ? wq : (w == 1) ? wk : (w == 2) ? wv : wo;
        floatx4 v = ((const floatx4*)src)[off];
        bf16x4 o;
#pragma unroll
        for (int r = 0; r < 4; ++r) o[r] = (bf16_t)v[r];
        ((bf16x4*)(Wb + (size_t)w * DIM * DIM))[off] = o;
        return;
    }
    i -= 4 * NW4;
    if (i < 2 * NX4) {
        const float* src = (i < NX4) ? q : k;
        bf16_t* dst = (i < NX4) ? qb : kb;
        const int off = (i < NX4) ? i : i - NX4;
        floatx4 v = ((const floatx4*)src)[off];
        bf16x4 o;
#pragma unroll
        for (int r = 0; r < 4; ++r) o[r] = (bf16_t)v[r];
        ((bf16x4*)dst)[off] = o;
        return;
    }
    i -= 2 * NX4;
    if (i < KS) {
        const int key = i;
        const int tk = key / 196;
        const int rem = key - tk * 196;
        const int hk = rem / 14;
        const int wk_ = rem - hk * 14;
#pragma unroll
        for (int c8 = 0; c8 < 8; ++c8) {
            bf16x8 v;
#pragma unroll
            for (int j = 0; j < 8; ++j) {
                const int e = c8 * 8 + j;
                const float f = (e == tk || e == 8 + hk || e == 22 + wk_) ? 1.f : 0.f;
                v[j] = (bf16_t)f;
            }
            *(bf16x8*)(koh + (size_t)key * 64 + c8 * 8) = v;
        }
        return;
    }
    i -= KS;
    if (i < TD * 8) {
        const int d = i >> 3;
        const int c8 = (i & 7) * 8;
        bf16x8 v;
#pragma unroll
        for (int j = 0; j < 8; ++j) {
            const int c = c8 + j;
            float f = 0.f;
            if (d < 15)      f = LOG2E * rpt[(size_t)d * 64 + c];
            else if (d < 42) f = LOG2E * rph[(size_t)(d - 15) * 64 + c];
            else if (d < 69) f = LOG2E * rpw[(size_t)(d - 42) * 64 + c];
            v[j] = (bf16_t)f;
        }
        *(bf16x8*)(Tt + (size_t)d * 64 + c8) = v;
    }
}

// ---------------------------------------------------------------------------
// Fused Q/K/V projection GEMM (unchanged): Y = X @ W^T + b, X bf16.
// Tile 128x64, BK=64 (12 bodies), dbuf async16 staging, XOR chunk swizzle.
// K output pre-scaled by SCALE_L2E.
// ---------------------------------------------------------------------------
__global__ __launch_bounds__(256) void gemm_qkv(
    const bf16_t* __restrict__ qb, const bf16_t* __restrict__ kb,
    const bf16_t* __restrict__ Wb,
    const float* __restrict__ bq, const float* __restrict__ bk,
    const float* __restrict__ bv,
    bf16_t* __restrict__ qhP, bf16_t* __restrict__ khP, bf16_t* __restrict__ vT)
{
    __shared__ __align__(16) bf16_t Asa[128 * 64];  // 16 KB each
    __shared__ __align__(16) bf16_t Asb[128 * 64];
    __shared__ __align__(16) bf16_t Bsa[64 * 64];   // 8 KB each
    __shared__ __align__(16) bf16_t Bsb[64 * 64];

    const int tid   = threadIdx.x;
    const int lane  = tid & 63;
    const int wave  = tid >> 6;
    const int row16 = lane & 15;
    const int quad  = lane >> 4;
    const int wm    = wave & 1;
    const int wn    = wave >> 1;
    const int m0 = blockIdx.x * 128;
    const int yb = blockIdx.y;
    const int proj = yb / 12;
    const int n0 = (yb - proj * 12) * 64;

    const bf16_t* X = (proj == 0) ? qb : kb;
    const bf16_t* W = Wb + (size_t)proj * DIM * DIM;
    const float* bias = (proj == 0) ? bq : (proj == 1) ? bk : bv;
    const float osc = (proj == 1) ? SCALE_L2E : 1.0f;

    floatx4 acc[4][2];
#pragma unroll
    for (int mt = 0; mt < 4; ++mt)
#pragma unroll
        for (int nt = 0; nt < 2; ++nt) acc[mt][nt] = (floatx4){0.f, 0.f, 0.f, 0.f};

    auto stage = [&](int k0, bf16_t* An, bf16_t* Bn) {
#pragma unroll
        for (int p = 0; p < 4; ++p) {
            const int s = p * 256 + tid;            // 0..1023: A 128 rows x 8 chunks
            const int row = s >> 3, c = s & 7;
            const int g = c ^ (row & 7);
            const int rowc = min(m0 + row, MROWS - 1);
            async16(X + (size_t)rowc * DIM + k0 + g * 8, An + s * 8);
        }
#pragma unroll
        for (int p = 0; p < 2; ++p) {
            const int s = p * 256 + tid;            // 0..511: B 64 rows x 8 chunks
            const int row = s >> 3, c = s & 7;
            const int g = c ^ (row & 7);
            async16(W + (size_t)(n0 + row) * DIM + k0 + g * 8, Bn + s * 8);
        }
    };

    auto body = [&](int k0, const bf16_t* Ac, const bf16_t* Bc,
                    bf16_t* An, bf16_t* Bn, bool pf) {
        __syncthreads();
        if (pf) stage(k0 + 64, An, Bn);
#pragma unroll
        for (int h = 0; h < 2; ++h) {
            const int pa = (h * 4 + quad) ^ (row16 & 7);
            bf16x8 aF[4], bF[2];
#pragma unroll
            for (int mt = 0; mt < 4; ++mt) {
                const int rowA = wm * 64 + mt * 16 + row16;
                aF[mt] = *(const bf16x8*)&Ac[rowA * 64 + pa * 8];
            }
#pragma unroll
            for (int nt = 0; nt < 2; ++nt) {
                const int rowB = wn * 32 + nt * 16 + row16;
                bF[nt] = *(const bf16x8*)&Bc[rowB * 64 + pa * 8];
            }
#pragma unroll
            for (int mt = 0; mt < 4; ++mt)
#pragma unroll
                for (int nt = 0; nt < 2; ++nt)
                    acc[mt][nt] = MFMA16(aF[mt], bF[nt], acc[mt][nt]);
        }
    };

    stage(0, Asa, Bsa);
    for (int ii = 0; ii < 6; ++ii) {
        const int k0 = ii * 128;
        body(k0,      Asa, Bsa, Asb, Bsb, true);
        body(k0 + 64, Asb, Bsb, Asa, Bsa, k0 + 128 < DIM);
    }

#pragma unroll
    for (int nt = 0; nt < 2; ++nt) {
        const int col = n0 + wn * 32 + nt * 16 + row16;
        const int head = col >> 6, cl = col & 63;
        const float bv_ = bias[col];
#pragma unroll
        for (int mt = 0; mt < 4; ++mt) {
            const int row0 = m0 + wm * 64 + mt * 16 + quad * 4;
            if (row0 < MROWS) {
                const int bb = (row0 >= KS) ? 1 : 0;
                const int key0 = row0 - bb * KS;
                if (proj == 2) {
                    bf16x4 pv;
#pragma unroll
                    for (int r = 0; r < 4; ++r) pv[r] = (bf16_t)(acc[mt][nt][r] + bv_);
                    *(bf16x4*)&vT[((size_t)(bb * NH + head) * 64 + cl) * KSP + key0] = pv;
                } else {
                    bf16_t* dst = (proj == 0) ? qhP : khP;
#pragma unroll
                    for (int r = 0; r < 4; ++r)
                        dst[((size_t)(bb * NH + head) * KS + key0 + r) * 64 + cl] =
                            (bf16_t)((acc[mt][nt][r] + bv_) * osc);
                }
            }
        }
    }
}

// ---------------------------------------------------------------------------
// Fused flash attention with MFMA-folded rel-pos bias — round-11 champion
// (passing, 198.35 µs total). In-block Qe prologue: MFMA (G = Q . T^T, C
// layout col=d row=qrow) into a Gs[64][81] f32 overlay on the not-yet-used
// Ks/Vs LDS, barrier, register gather, barrier, THEN stageKV(0). The
// conservative ordering — r12's stage-0-early variant raced (absmax fail).
// Main loop byte-identical to the r4/r10 champion.
// ---------------------------------------------------------------------------
__global__ __launch_bounds__(256, 2) void attn_fused(
    const bf16_t* __restrict__ qhP, const bf16_t* __restrict__ khP,
    const bf16_t* __restrict__ koh, const bf16_t* __restrict__ vT,
    const bf16_t* __restrict__ Tt, bf16_t* __restrict__ ao)
{
    __shared__ __align__(16) unsigned char smem[29696];
    bf16_t* const KsA = (bf16_t*)(smem);            // 8 KB  K~ tile A
    bf16_t* const KsB = (bf16_t*)(smem + 8192);     // 8 KB  K~ tile B
    bf16_t* const VsA = (bf16_t*)(smem + 16384);    // 4 KB  V tile A
    bf16_t* const VsB = (bf16_t*)(smem + 20480);    // 4 KB  V tile B
    bf16_t* const Pl  = (bf16_t*)(smem + 24576);    // 5 KB  per-wave P
    float (*const Gs)[81] = (float(*)[81])smem;     // prologue overlay 20.7 KB

    const int tid   = threadIdx.x;
    const int lane  = tid & 63;
    const int wave  = tid >> 6;
    const int row16 = lane & 15;
    const int quad  = lane >> 4;

    // XCD swizzle: all 25 q-blocks of one (b,n) share blockIdx%8
    const int L = blockIdx.x;           // 0..599 (= 8 * 3 * 25)
    const int xcd = L & 7;
    const int j = L >> 3;               // 0..74
    const int bn = xcd * 3 + (j % 3);   // 0..23
    const int q0 = (j / 3) * 64;        // 25 tiles of 64 rows (last half-masked)
    const int b = bn / NH;
    const int n = bn - b * NH;

    const int qrow = min(q0 + wave * 16 + row16, QS - 1);
    const bf16_t* qp = qhP + ((size_t)bn * QS + qrow) * 64 + quad * 8;
    bf16x8 aQ0 = *(const bf16x8*)(qp);
    bf16x8 aQ1 = *(const bf16x8*)(qp + 32);

    // ---- prologue: in-block Qe (was the qext kernel) -----------------------
    {
        floatx4 g[5];
#pragma unroll
        for (int t = 0; t < 5; ++t) {
            const bf16_t* tp = Tt + (size_t)(t * 16 + row16) * 64 + quad * 8;
            floatx4 s = (floatx4){0.f, 0.f, 0.f, 0.f};
            s = MFMA16(aQ0, *(const bf16x8*)(tp), s);
            s = MFMA16(aQ1, *(const bf16x8*)(tp + 32), s);
            g[t] = s;
        }
#pragma unroll
        for (int t = 0; t < 5; ++t)
#pragma unroll
            for (int r = 0; r < 4; ++r)
                Gs[wave * 16 + quad * 4 + r][t * 16 + row16] = g[t][r];
    }
    __syncthreads();
    bf16x8 aQ2, aQ3;
    {
        const int lrow = wave * 16 + row16;      // Gs row for this lane's qrow
        const int tq = qrow / 196;
        const int rem = qrow - tq * 196;
        const int hq = rem / 14;
        const int wq = rem - hq * 14;
#pragma unroll
        for (int jj = 0; jj < 8; ++jj) {
            const int e = quad * 8 + jj;         // 0..31, all < 36
            const int d = (e < 8)  ? (tq + 7 - e)
                        : (e < 22) ? (hq + 36 - e)
                                   : (wq + 77 - e);
            aQ2[jj] = (bf16_t)Gs[lrow][d];
        }
#pragma unroll
        for (int jj = 0; jj < 8; ++jj) {
            float v = 0.f;
            if (quad == 0 && jj < 4)             // e = 32..35 (w-branch); else 0
                v = Gs[lrow][wq + 77 - (32 + jj)];
            aQ3[jj] = (bf16_t)v;
        }
    }
    __syncthreads();   // all Gs reads done before stageKV(0) overwrites smem

    // ---- main loop (byte-identical to round 10) ----------------------------
    floatx4 O[4];
#pragma unroll
    for (int ct = 0; ct < 4; ++ct) O[ct] = (floatx4){0.f, 0.f, 0.f, 0.f};
    float lsum[4] = {0.f, 0.f, 0.f, 0.f};

    const bf16_t* khb = khP + (size_t)bn * KS * 64;
    const bf16_t* vTb = vT + (size_t)bn * 64 * KSP;
    const int pbase = wave * 16 * 40;
    const int sw3 = row16 & 7;          // K~ read swizzle
    const int sw2 = (row16 >> 1) & 3;   // V read swizzle

    auto stageKV = [&](int k0, bf16_t* Kn, bf16_t* Vn) {
#pragma unroll
        for (int p = 0; p < 2; ++p) {
            const int s = p * 256 + tid;            // 0..511
            const int row = s >> 4, c = s & 15;
            const int l = c ^ (row & 7);            // low-3-bit XOR keeps halves
            const bf16_t* src = (l < 8)
                ? khb + (size_t)(k0 + row) * 64 + l * 8
                : koh + (size_t)(k0 + row) * 64 + (l - 8) * 8;
            async16(src, Kn + s * 8);
        }
        {
            const int row = tid >> 2, c = tid & 3;  // 64 rows x 4 chunks
            const int l = c ^ ((row >> 1) & 3);
            async16(vTb + (size_t)row * KSP + k0 + l * 8, Vn + tid * 8);
        }
    };

    auto iter = [&](int ki, const bf16_t* Kc, const bf16_t* Vc,
                    bf16_t* Kn, bf16_t* Vn, bool pf) {
        const int k0 = ki * KT;
        __syncthreads();   // stage(ki) landed (vmcnt drain); prior readers done
        if (pf) stageKV(k0 + KT, Kn, Vn);   // lands during THIS tile's compute

        floatx4 S[2];
#pragma unroll
        for (int t = 0; t < 2; ++t) {
            const bf16_t* kp_ = &Kc[(t * 16 + row16) * 128];
            floatx4 s = (floatx4){0.f, 0.f, 0.f, 0.f};
            s = MFMA16(aQ0, *(const bf16x8*)&kp_[((0 + quad) ^ sw3) * 8], s);
            s = MFMA16(aQ1, *(const bf16x8*)&kp_[((4 + quad) ^ sw3) * 8], s);
            s = MFMA16(aQ2, *(const bf16x8*)&kp_[((8 + quad) ^ sw3) * 8], s);
            s = MFMA16(aQ3, *(const bf16x8*)&kp_[((12 + quad) ^ sw3) * 8], s);
            S[t] = s;
        }

#pragma unroll
        for (int t = 0; t < 2; ++t) {
#pragma unroll
            for (int r = 0; r < 4; ++r) {
                float p = __builtin_amdgcn_exp2f(S[t][r]);
                lsum[r] += p;
                Pl[pbase + (quad * 4 + r) * 40 + t * 16 + row16] = (bf16_t)p;
            }
        }

        bf16x8 aP = *(const bf16x8*)&Pl[pbase + row16 * 40 + quad * 8];
#pragma unroll
        for (int ct = 0; ct < 4; ++ct) {
            bf16x8 bV = *(const bf16x8*)&Vc[(ct * 16 + row16) * 32 + (quad ^ sw2) * 8];
            O[ct] = MFMA16(aP, bV, O[ct]);
        }
    };

    stageKV(0, KsA, VsA);
#pragma unroll 1
    for (int kp2 = 0; kp2 < 24; ++kp2) {
        iter(2 * kp2,     KsA, VsA, KsB, VsB, true);
        iter(2 * kp2 + 1, KsB, VsB, KsA, VsA, true);
    }
    iter(48, KsA, VsA, KsB, VsB, false);

    // ---- epilogue: reduce l across the 16-lane key group, normalize, store
    float inv[4];
#pragma unroll
    for (int r = 0; r < 4; ++r) {
        float l = lsum[r];
        l += __shfl_xor(l, 1);
        l += __shfl_xor(l, 2);
        l += __shfl_xor(l, 4);
        l += __shfl_xor(l, 8);
        inv[r] = 1.f / l;
    }
#pragma unroll
    for (int ct = 0; ct < 4; ++ct) {
        const int c = n * HD + ct * 16 + row16;
#pragma unroll
        for (int r = 0; r < 4; ++r) {
            const int qr = q0 + wave * 16 + quad * 4 + r;
            if (qr < QS)
                ao[(size_t)(b * QS + qr) * DIM + c] = (bf16_t)(O[ct][r] * inv[r]);
        }
    }
}

// ---------------------------------------------------------------------------
// O-projection GEMM (unchanged, 64x64 tile, 588 blocks = 2.3/CU):
// Y(f32) = X(bf16) @ Wo^T + bo.
// ---------------------------------------------------------------------------
__global__ __launch_bounds__(256) void gemm_o(
    const bf16_t* __restrict__ X, const bf16_t* __restrict__ W,
    const float* __restrict__ bias, float* __restrict__ Y)
{
    __shared__ __align__(16) bf16_t Asa[64 * 64];
    __shared__ __align__(16) bf16_t Asb[64 * 64];
    __shared__ __align__(16) bf16_t Bsa[64 * 64];
    __shared__ __align__(16) bf16_t Bsb[64 * 64];

    const int tid   = threadIdx.x;
    const int lane  = tid & 63;
    const int wave  = tid >> 6;
    const int row16 = lane & 15;
    const int quad  = lane >> 4;
    const int m0 = blockIdx.x * 64;
    const int n0 = blockIdx.y * 64;

    floatx4 acc[4];
#pragma unroll
    for (int nt = 0; nt < 4; ++nt) acc[nt] = (floatx4){0.f, 0.f, 0.f, 0.f};

    auto stage = [&](int k0, bf16_t* An, bf16_t* Bn) {
#pragma unroll
        for (int p = 0; p < 2; ++p) {
            const int s = p * 256 + tid;
            const int row = s >> 3, pc = s & 7;
            const int g = pc ^ (row & 7);
            async16(X + (size_t)(m0 + row) * DIM + k0 + g * 8, An + s * 8);
            async16(W + (size_t)(n0 + row) * DIM + k0 + g * 8, Bn + s * 8);
        }
    };

    auto body = [&](int k0, const bf16_t* Ac, const bf16_t* Bc,
                    bf16_t* An, bf16_t* Bn, bool pf) {
        __syncthreads();
        if (pf) stage(k0 + 64, An, Bn);
#pragma unroll
        for (int h = 0; h < 2; ++h) {
            const int lc = h * 4 + quad;
            const int pa = lc ^ (row16 & 7);
            const int rowA = wave * 16 + row16;
            bf16x8 aF = *(const bf16x8*)&Ac[rowA * 64 + pa * 8];
#pragma unroll
            for (int nt = 0; nt < 4; ++nt) {
                bf16x8 bF = *(const bf16x8*)&Bc[(nt * 16 + row16) * 64 + pa * 8];
                acc[nt] = MFMA16(aF, bF, acc[nt]);
            }
        }
    };

    stage(0, Asa, Bsa);
    for (int ii = 0; ii < 6; ++ii) {
        const int k0 = ii * 128;
        body(k0,      Asa, Bsa, Asb, Bsb, true);
        body(k0 + 64, Asb, Bsb, Asa, Bsa, k0 + 128 < DIM);
    }

#pragma unroll
    for (int nt = 0; nt < 4; ++nt) {
        const int col = n0 + nt * 16 + row16;
        const float bv = bias[col];
#pragma unroll
        for (int r = 0; r < 4; ++r) {
            const int row = m0 + wave * 16 + quad * 4 + r;
            Y[(size_t)row * DIM + col] = acc[nt][r] + bv;
        }
    }
}

// ---------------------------------------------------------------------------
extern "C" void kernel_launch(void* const* d_in, const int* in_sizes, int n_in,
                              void* d_out, int out_size, void* d_ws, size_t ws_size,
                              hipStream_t stream) {
    const float* q   = (const float*)d_in[0];
    const float* k   = (const float*)d_in[1];
    const float* Wq  = (const float*)d_in[2];
    const float* bq  = (const float*)d_in[3];
    const float* Wk  = (const float*)d_in[4];
    const float* bk  = (const float*)d_in[5];
    const float* Wv  = (const float*)d_in[6];
    const float* bv  = (const float*)d_in[7];
    const float* Wo  = (const float*)d_in[8];
    const float* bo  = (const float*)d_in[9];
    const float* rpt = (const float*)d_in[10];
    const float* rph = (const float*)d_in[11];
    const float* rpw = (const float*)d_in[12];

    // workspace (~29.3 MB). Aliases (stream-order lifetimes disjoint):
    //   kbuf: kb (read by gemm_qkv)
    //   aoQb: qb (read by gemm_qkv) then ao (written by attn)
    bf16_t* qhP  = (bf16_t*)d_ws;
    bf16_t* khP  = qhP  + (size_t)MROWS * DIM;
    bf16_t* vT   = khP  + (size_t)MROWS * DIM;
    bf16_t* kbuf = vT   + (size_t)BB * NH * HD * KSP;
    bf16_t* aoQb = kbuf + (size_t)MROWS * DIM;
    bf16_t* koh  = aoQb + (size_t)MROWS * DIM;
    bf16_t* Tt   = koh  + (size_t)KS * 64;
    bf16_t* Wb   = Tt   + (size_t)TD * 64;        // [Wq|Wk|Wv|Wo]

    const int NW4 = DIM * DIM / 4;
    const int NX4 = MROWS * DIM / 4;
    const int NCVT = 4 * NW4 + 2 * NX4 + KS + TD * 8;
    cvt_w<<<(NCVT + 255) / 256, 256, 0, stream>>>(
        q, k, Wq, Wk, Wv, Wo, rpt, rph, rpw, Wb, aoQb, kbuf, koh, Tt);

    gemm_qkv<<<dim3(25, 36), 256, 0, stream>>>(
        aoQb, kbuf, Wb, bq, bk, bv, qhP, khP, vT);

    attn_fused<<<dim3(8 * 3 * 25), 256, 0, stream>>>(
        qhP, khP, koh, vT, Tt, aoQb);

    gemm_o<<<dim3(MROWS / 64, DIM / 64), 256, 0, stream>>>(
        aoQb, Wb + (size_t)3 * DIM * DIM, bo, (float*)d_out);
}